// Round 9
// baseline (699.071 us; speedup 1.0000x reference)
//
#include <hip/hip_runtime.h>
#include <hip/hip_bf16.h>
#include <math.h>

#define B 2

typedef __attribute__((ext_vector_type(8))) short bf16x8;
typedef __attribute__((ext_vector_type(4))) float f32x4;

// bf16 RNE on raw bits (inputs have no NaN/Inf)
__device__ __forceinline__ unsigned short f2bf(float f) {
  unsigned int u = __float_as_uint(f);
  return (unsigned short)((u + 0x7FFFu + ((u >> 16) & 1u)) >> 16);
}
__device__ __forceinline__ float bf2f(unsigned short h) {
  return __uint_as_float((unsigned int)h << 16);
}

typedef unsigned short u16;

// ---------------- dtype probe: flag=1 if buffer is bf16, 0 if f32 ----------------
__global__ void probe_kernel(const unsigned short* __restrict__ x, int* __restrict__ flag) {
  if (threadIdx.x == 0 && blockIdx.x == 0) {
    int sane = 0;
    for (int i = 0; i < 512; ++i) {
      int e = (x[i] >> 7) & 0xFF;
      if (e >= 97 && e <= 157) ++sane;
    }
    flag[0] = (sane >= 480) ? 1 : 0;
  }
}

// =============== conv5 via split-bf16 MFMA, conversion+im2col FUSED into staging ====
// x -> hi = bf16(x), lo = bf16(x - hi); A.B ~= Ah.Bh + Ah.Bl + Al.Bh

struct hl8 { bf16x8 h, l; };

// A (W) loader: K-contiguous row read + in-register split.
__device__ __forceinline__ hl8 loadA(
    const float* __restrict__ Wf, const u16* __restrict__ Wb,
    int isbf, int oc, int kg)
{
  hl8 r;
  if (isbf) {
    r.h = *(const bf16x8*)(Wb + (size_t)oc * 18432 + kg);
    r.l = (bf16x8){0,0,0,0,0,0,0,0};
  } else {
    const float* p = Wf + (size_t)oc * 18432 + kg;
    float4 f0 = *(const float4*)p;
    float4 f1 = *(const float4*)(p + 4);
    float ff[8] = {f0.x, f0.y, f0.z, f0.w, f1.x, f1.y, f1.z, f1.w};
#pragma unroll
    for (int i = 0; i < 8; ++i) {
      u16 h = f2bf(ff[i]);
      r.h[i] = (short)h;
      r.l[i] = (short)f2bf(ff[i] - bf2f(h));
    }
  }
  return r;
}

// B (im2col of c4) loader: K = c*9 + t, 3x3 pad 1 around (y,x) in 16x16.
__device__ __forceinline__ hl8 loadB(
    const float* __restrict__ Cf, const u16* __restrict__ Cb,
    int isbf, int n, int y, int x, int kg)
{
  hl8 r;
#pragma unroll
  for (int i = 0; i < 8; ++i) {
    unsigned K = (unsigned)(kg + i);
    unsigned c = K / 9u;            // compiler magic-div
    unsigned t = K - c * 9u;
    int yy = y + (int)(t / 3u) - 1;
    int xx = x + (int)(t % 3u) - 1;
    bool in = (yy >= 0 && yy < 16 && xx >= 0 && xx < 16);
    size_t src = in ? ((((size_t)n * 2048 + c) << 8) + yy * 16 + xx) : 0;
    if (isbf) {
      u16 h = in ? Cb[src] : (u16)0;
      r.h[i] = (short)h;
      r.l[i] = 0;
    } else {
      float v = in ? Cf[src] : 0.f;
      u16 h = f2bf(v);
      r.h[i] = (short)h;
      r.l[i] = (short)f2bf(v - bf2f(h));
    }
  }
  return r;
}

// LDS XOR swizzle: permute 16B slots within each 128B row (involution, both sides).
__device__ __forceinline__ int swz(int b) { return b ^ (((b >> 7) & 7) << 4); }

// GEMM: part[ks][oc][r] over K-slice ks; M=N=512, K=18432, 8 slices of 2304.
// 64x64 tiles; staging reads W and c4 DIRECTLY (both dtypes), split in-register.
__global__ __launch_bounds__(256) void conv5_gemm_fused_kernel(
    const float* __restrict__ Wf, const u16* __restrict__ Wb,
    const float* __restrict__ Cf, const u16* __restrict__ Cb,
    float* __restrict__ part, const int* __restrict__ flag)
{
  const int isbf = flag[0];
  const int tile = blockIdx.x;            // 0..63 over 8x8 tiles
  const int ks   = blockIdx.y;            // 0..7 split-K
  const int mo = (tile >> 3) * 64;        // oc tile base
  const int no = (tile & 7) * 64;         // r tile base
  const int kb = ks * 2304;
  const int tid = threadIdx.x;
  const int w = tid >> 6, lane = tid & 63;
  const int wr = w >> 1, wc = w & 1;      // 2x2 wave grid, each wave 32x32 out

  __shared__ unsigned short sAh[4096], sAl[4096], sBh[4096], sBl[4096];  // 32 KB

  const int row0 = tid >> 3, slot = tid & 7;
  const int kg0 = kb + slot * 8;
  // A rows
  const int aoc0 = mo + row0, aoc1 = aoc0 + 32;
  // B rows (im2col coords)
  const int r0 = no + row0, r1 = r0 + 32;
  const int bn0 = r0 >> 8, bpx0 = r0 & 255;
  const int bn1 = r1 >> 8, bpx1 = r1 & 255;
  const int bx0 = bpx0 & 15, by0 = bpx0 >> 4;
  const int bx1 = bpx1 & 15, by1 = bpx1 >> 4;

  const int w0 = swz(row0 * 128 + slot * 16);
  const int w1 = swz((row0 + 32) * 128 + slot * 16);

  f32x4 acc[2][2];
#pragma unroll
  for (int m = 0; m < 2; ++m)
#pragma unroll
    for (int nn = 0; nn < 2; ++nn) acc[m][nn] = (f32x4){0.f, 0.f, 0.f, 0.f};

  // prefetch first K-step
  hl8 ra0 = loadA(Wf, Wb, isbf, aoc0, kg0);
  hl8 ra1 = loadA(Wf, Wb, isbf, aoc1, kg0);
  hl8 rb0 = loadB(Cf, Cb, isbf, bn0, by0, bx0, kg0);
  hl8 rb1 = loadB(Cf, Cb, isbf, bn1, by1, bx1, kg0);

  const int arow = wr * 32 + (lane & 15);
  const int brow = wc * 32 + (lane & 15);
  const int cb = (lane >> 4) * 16;

  for (int kk = 0; kk < 2304; kk += 64) {
    *(bf16x8*)((char*)sAh + w0) = ra0.h;  *(bf16x8*)((char*)sAh + w1) = ra1.h;
    *(bf16x8*)((char*)sAl + w0) = ra0.l;  *(bf16x8*)((char*)sAl + w1) = ra1.l;
    *(bf16x8*)((char*)sBh + w0) = rb0.h;  *(bf16x8*)((char*)sBh + w1) = rb1.h;
    *(bf16x8*)((char*)sBl + w0) = rb0.l;  *(bf16x8*)((char*)sBl + w1) = rb1.l;
    if (kk + 64 < 2304) {
      const int kg = kg0 + kk + 64;
      ra0 = loadA(Wf, Wb, isbf, aoc0, kg);
      ra1 = loadA(Wf, Wb, isbf, aoc1, kg);
      rb0 = loadB(Cf, Cb, isbf, bn0, by0, bx0, kg);
      rb1 = loadB(Cf, Cb, isbf, bn1, by1, bx1, kg);
    }
    __syncthreads();
#pragma unroll
    for (int k2 = 0; k2 < 2; ++k2) {
      const int colb = k2 * 64 + cb;
      bf16x8 fah[2], fal[2], fbh[2], fbl[2];
#pragma unroll
      for (int m = 0; m < 2; ++m) {
        fah[m] = *(const bf16x8*)((char*)sAh + swz((arow + m * 16) * 128 + colb));
        fal[m] = *(const bf16x8*)((char*)sAl + swz((arow + m * 16) * 128 + colb));
      }
#pragma unroll
      for (int nn = 0; nn < 2; ++nn) {
        fbh[nn] = *(const bf16x8*)((char*)sBh + swz((brow + nn * 16) * 128 + colb));
        fbl[nn] = *(const bf16x8*)((char*)sBl + swz((brow + nn * 16) * 128 + colb));
      }
#pragma unroll
      for (int m = 0; m < 2; ++m)
#pragma unroll
        for (int nn = 0; nn < 2; ++nn) {
          acc[m][nn] = __builtin_amdgcn_mfma_f32_16x16x32_bf16(fah[m], fbh[nn], acc[m][nn], 0, 0, 0);
          acc[m][nn] = __builtin_amdgcn_mfma_f32_16x16x32_bf16(fah[m], fbl[nn], acc[m][nn], 0, 0, 0);
          acc[m][nn] = __builtin_amdgcn_mfma_f32_16x16x32_bf16(fal[m], fbh[nn], acc[m][nn], 0, 0, 0);
        }
    }
    __syncthreads();
  }

  // C/D layout: col = lane&15 (-> r), row = (lane>>4)*4 + j (-> oc)
#pragma unroll
  for (int m = 0; m < 2; ++m)
#pragma unroll
    for (int nn = 0; nn < 2; ++nn) {
      const int r = no + wc * 32 + nn * 16 + (lane & 15);
      const int n = r >> 8, px = r & 255;
#pragma unroll
      for (int j = 0; j < 4; ++j) {
        const int oc = mo + wr * 32 + m * 16 + (lane >> 4) * 4 + j;
        part[(size_t)ks * 262144 + ((size_t)n * 512 + oc) * 256 + px] = acc[m][nn][j];
      }
    }
}

// sum 8 K-slices + BN + ReLU -> t5
__global__ __launch_bounds__(256) void finalize5_kernel(
    const float* __restrict__ part, const float* __restrict__ bnf,
    const unsigned short* __restrict__ bnb, float* __restrict__ t5,
    const int* __restrict__ flag)
{
  int idx = blockIdx.x * 256 + threadIdx.x;   // 262144 total
  int oc = (idx >> 8) & 511;
  float s = 0.f;
#pragma unroll
  for (int q = 0; q < 8; ++q) s += part[(size_t)q * 262144 + idx];
  float g, b, m, v;
  if (flag[0]) {
    g = bf2f(bnb[oc]); b = bf2f(bnb[512 + oc]);
    m = bf2f(bnb[1024 + oc]); v = bf2f(bnb[1536 + oc]);
  } else {
    g = bnf[oc]; b = bnf[512 + oc]; m = bnf[1024 + oc]; v = bnf[1536 + oc];
  }
  float sc = g * rsqrtf(v + 1e-5f);
  float val = s * sc + (b - m * sc);
  t5[idx] = fmaxf(val, 0.f);
}

// ---------------- split-C 1x1 conv partials (vectorized + reg double-buffer) --------
// blockIdx.z = n*KS + kc; part[kc*(B*O*S) + (n*O + o)*S + s]
__global__ __launch_bounds__(256) void conv1x1_part_kernel(
    const float* __restrict__ Xf, const unsigned short* __restrict__ Xb,
    const float* __restrict__ Wf, const unsigned short* __restrict__ Wb,
    float* __restrict__ part, int C, int O, int S, int KS, int xf32,
    const int* __restrict__ flag)
{
  const int isbf = flag[0];
  const int xbf = xf32 ? 0 : isbf;
  const int tid = threadIdx.x;
  const int sg = tid & 15, og = tid >> 4;
  const int s0 = blockIdx.x * 64;
  const int o0 = blockIdx.y * 64;
  const int n  = blockIdx.z / KS;
  const int kc = blockIdx.z % KS;
  const int CC = C / KS;
  const int cbase = kc * CC;

  __shared__ float xs[16][64];
  __shared__ float wsT[16][68];

  // load map: X tile = 256 x float4 (16B/lane), W tile likewise
  const int xc  = tid >> 4;          // 0..15 channel within tile
  const int xs4 = (tid & 15) * 4;    // s offset
  const int wo  = tid >> 2;          // 0..63 o within tile
  const int wc4 = (tid & 3) * 4;     // c offset within tile
  const int owo = o0 + wo;
  const bool wok = (owo < O);

  float acc[4][4];
#pragma unroll
  for (int i = 0; i < 4; ++i)
#pragma unroll
    for (int j = 0; j < 4; ++j) acc[i][j] = 0.f;

  // ---- prefetch first tile into registers ----
  float4 xr, wr_;
  {
    const int c0 = cbase;
    if (xbf) {
      ushort4 u = *(const ushort4*)(Xb + ((size_t)n * C + c0 + xc) * S + s0 + xs4);
      xr.x = bf2f(u.x); xr.y = bf2f(u.y); xr.z = bf2f(u.z); xr.w = bf2f(u.w);
    } else {
      xr = *(const float4*)(Xf + ((size_t)n * C + c0 + xc) * S + s0 + xs4);
    }
    if (wok) {
      if (isbf) {
        ushort4 u = *(const ushort4*)(Wb + (size_t)owo * C + c0 + wc4);
        wr_.x = bf2f(u.x); wr_.y = bf2f(u.y); wr_.z = bf2f(u.z); wr_.w = bf2f(u.w);
      } else {
        wr_ = *(const float4*)(Wf + (size_t)owo * C + c0 + wc4);
      }
    } else { wr_.x = 0.f; wr_.y = 0.f; wr_.z = 0.f; wr_.w = 0.f; }
  }

  for (int c0 = cbase; c0 < cbase + CC; c0 += 16) {
    // write staged regs -> LDS
    *(float4*)&xs[xc][xs4] = xr;
    wsT[wc4 + 0][wo] = wr_.x;
    wsT[wc4 + 1][wo] = wr_.y;
    wsT[wc4 + 2][wo] = wr_.z;
    wsT[wc4 + 3][wo] = wr_.w;
    __syncthreads();
    // issue next-tile loads early; they fly under the FMA block
    if (c0 + 16 < cbase + CC) {
      const int c1 = c0 + 16;
      if (xbf) {
        ushort4 u = *(const ushort4*)(Xb + ((size_t)n * C + c1 + xc) * S + s0 + xs4);
        xr.x = bf2f(u.x); xr.y = bf2f(u.y); xr.z = bf2f(u.z); xr.w = bf2f(u.w);
      } else {
        xr = *(const float4*)(Xf + ((size_t)n * C + c1 + xc) * S + s0 + xs4);
      }
      if (wok) {
        if (isbf) {
          ushort4 u = *(const ushort4*)(Wb + (size_t)owo * C + c1 + wc4);
          wr_.x = bf2f(u.x); wr_.y = bf2f(u.y); wr_.z = bf2f(u.z); wr_.w = bf2f(u.w);
        } else {
          wr_ = *(const float4*)(Wf + (size_t)owo * C + c1 + wc4);
        }
      }
    }
#pragma unroll
    for (int c = 0; c < 16; ++c) {
      const float4 xv = *(const float4*)&xs[c][sg * 4];
      const float4 wv = *(const float4*)&wsT[c][og * 4];
      acc[0][0] = fmaf(wv.x, xv.x, acc[0][0]);
      acc[0][1] = fmaf(wv.x, xv.y, acc[0][1]);
      acc[0][2] = fmaf(wv.x, xv.z, acc[0][2]);
      acc[0][3] = fmaf(wv.x, xv.w, acc[0][3]);
      acc[1][0] = fmaf(wv.y, xv.x, acc[1][0]);
      acc[1][1] = fmaf(wv.y, xv.y, acc[1][1]);
      acc[1][2] = fmaf(wv.y, xv.z, acc[1][2]);
      acc[1][3] = fmaf(wv.y, xv.w, acc[1][3]);
      acc[2][0] = fmaf(wv.z, xv.x, acc[2][0]);
      acc[2][1] = fmaf(wv.z, xv.y, acc[2][1]);
      acc[2][2] = fmaf(wv.z, xv.z, acc[2][2]);
      acc[2][3] = fmaf(wv.z, xv.w, acc[2][3]);
      acc[3][0] = fmaf(wv.w, xv.x, acc[3][0]);
      acc[3][1] = fmaf(wv.w, xv.y, acc[3][1]);
      acc[3][2] = fmaf(wv.w, xv.z, acc[3][2]);
      acc[3][3] = fmaf(wv.w, xv.w, acc[3][3]);
    }
    __syncthreads();
  }

  const size_t BOS = (size_t)B * O * S;
#pragma unroll
  for (int i = 0; i < 4; ++i) {
    int o = o0 + og * 4 + i;
    if (o < O) {
      float4 r;
      r.x = acc[i][0]; r.y = acc[i][1]; r.z = acc[i][2]; r.w = acc[i][3];
      *(float4*)(part + (size_t)kc * BOS + ((size_t)n * O + o) * S + s0 + sg * 4) = r;
    }
  }
}

// sum KS partials + optional BN -> Y.  total = B*O*S
__global__ __launch_bounds__(256) void reduce_bn_kernel(
    const float* __restrict__ part, const float* __restrict__ bnf,
    const unsigned short* __restrict__ bnb, int hasbn,
    float* __restrict__ Y, int O, int S, int KS, int total,
    const int* __restrict__ flag)
{
  int idx = blockIdx.x * 256 + threadIdx.x;
  if (idx >= total) return;
  float s = 0.f;
  for (int kc = 0; kc < KS; ++kc) s += part[(size_t)kc * total + idx];
  float sc = 1.f, sh = 0.f;
  if (hasbn) {
    int o = (idx / S) % O;
    float g, b, m, v;
    if (flag[0]) {
      g = bf2f(bnb[o]); b = bf2f(bnb[O + o]);
      m = bf2f(bnb[2 * O + o]); v = bf2f(bnb[3 * O + o]);
    } else {
      g = bnf[o]; b = bnf[O + o]; m = bnf[2 * O + o]; v = bnf[3 * O + o];
    }
    sc = g * rsqrtf(v + 1e-5f);
    sh = b - m * sc;
  }
  Y[idx] = s * sc + sh;
}

// ---------------- bilinear 2x upsample, align_corners=True ----------------
__global__ __launch_bounds__(256) void upsample2x_kernel(
    const float* __restrict__ in, float* __restrict__ out,
    int h, int w, int total)
{
  int idx = blockIdx.x * 256 + threadIdx.x;
  if (idx >= total) return;
  const int Wd = 2 * w, Hd = 2 * h;
  int xo = idx % Wd;
  int t  = idx / Wd;
  int yo = t % Hd;
  int pl = t / Hd;
  const float rh = (float)(h - 1) / (float)(Hd - 1);
  const float rw = (float)(w - 1) / (float)(Wd - 1);
  float fy = yo * rh, fx = xo * rw;
  int y0 = (int)fy; if (y0 > h - 1) y0 = h - 1;
  int x0 = (int)fx; if (x0 > w - 1) x0 = w - 1;
  int y1 = min(y0 + 1, h - 1), x1 = min(x0 + 1, w - 1);
  float wy = fy - y0, wx = fx - x0;
  const float* p = in + (size_t)pl * h * w;
  float v00 = p[y0 * w + x0], v01 = p[y0 * w + x1];
  float v10 = p[y1 * w + x0], v11 = p[y1 * w + x1];
  out[idx] = (v00 * (1.f - wy) + v10 * wy) * (1.f - wx) +
             (v01 * (1.f - wy) + v11 * wy) * wx;
}

// ---- kd-split attention: partial dots.  pd[((kc*B + n)*9 + j)*S + p] ----
__global__ __launch_bounds__(256) void att_part_kernel(
    const float* __restrict__ q, const float* __restrict__ k,
    float* __restrict__ pd, int kd, int H, int Wd, int KC, int total)
{
  int idx = blockIdx.x * 256 + threadIdx.x;
  if (idx >= total) return;
  const int S = H * Wd;
  int p = idx % S;
  int t = idx / S;
  int n = t % B, kc = t / B;
  int x = p % Wd, y = p / Wd;
  int off[9]; bool ok[9];
#pragma unroll
  for (int j = 0; j < 9; ++j) {
    int dy = (j / 3) * 2 - 2, dx = (j % 3) * 2 - 2;
    int yy = y + dy, xx = x + dx;
    ok[j] = (yy >= 0 && yy < H && xx >= 0 && xx < Wd);
    off[j] = yy * Wd + xx;
  }
  float dot[9] = {0.f,0.f,0.f,0.f,0.f,0.f,0.f,0.f,0.f};
  const int cc = kd / KC;
  const int c0 = kc * cc;
  const float* qp = q + (size_t)n * kd * S + p;
  const float* kp = k + (size_t)n * kd * S;
  for (int c = c0; c < c0 + cc; ++c) {
    float qv = qp[(size_t)c * S];
    const float* kcp = kp + (size_t)c * S;
#pragma unroll
    for (int j = 0; j < 9; ++j)
      if (ok[j]) dot[j] = fmaf(qv, kcp[off[j]], dot[j]);
  }
  float* o = pd + ((size_t)(kc * B + n) * 9) * S + p;
#pragma unroll
  for (int j = 0; j < 9; ++j) o[(size_t)j * S] = dot[j];
}

// sum partial dots + softmax.  total = B*S
__global__ __launch_bounds__(256) void att_fin_kernel(
    const float* __restrict__ pd, float* __restrict__ att,
    int KC, int S, int total)
{
  int idx = blockIdx.x * 256 + threadIdx.x;
  if (idx >= total) return;
  int p = idx % S, n = idx / S;
  float dot[9] = {0.f,0.f,0.f,0.f,0.f,0.f,0.f,0.f,0.f};
  for (int kc = 0; kc < KC; ++kc) {
    const float* o = pd + ((size_t)(kc * B + n) * 9) * S + p;
#pragma unroll
    for (int j = 0; j < 9; ++j) dot[j] += o[(size_t)j * S];
  }
  float m = dot[0];
#pragma unroll
  for (int j = 1; j < 9; ++j) m = fmaxf(m, dot[j]);
  float e[9], ssum = 0.f;
#pragma unroll
  for (int j = 0; j < 9; ++j) { e[j] = __expf(dot[j] - m); ssum += e[j]; }
  float inv = 1.f / ssum;
#pragma unroll
  for (int j = 0; j < 9; ++j)
    att[((size_t)n * 9 + j) * S + p] = e[j] * inv;
}

// ---- tap-apply on PRE-UPSAMPLED prev: out[n,c,p] = sum_j att_j[p]*prevUp[n,c,p+D_j]
// 4 channels/thread; taps are dilation-2 shifts at the SAME resolution (coalesced).
__global__ __launch_bounds__(256) void apply_tap4_kernel(
    const float* __restrict__ att, const float* __restrict__ prevUp,
    float* __restrict__ out, int C, int H, int Wd, int total4)
{
  int idx = blockIdx.x * 256 + threadIdx.x;
  if (idx >= total4) return;
  const int S = H * Wd;
  const int CQ = C >> 2;
  int p = idx % S;
  int t = idx / S;
  int cq = t % CQ, n = t / CQ;
  int c0 = cq << 2;
  int x = p % Wd, y = p / Wd;
  const float* ap = att + (size_t)n * 9 * S + p;
  float a[9]; int off[9];
#pragma unroll
  for (int j = 0; j < 9; ++j) {
    int dy = (j / 3) * 2 - 2, dx = (j % 3) * 2 - 2;
    int yy = y + dy, xx = x + dx;
    bool ok = (yy >= 0 && yy < H && xx >= 0 && xx < Wd);
    a[j]   = ok ? ap[(size_t)j * S] : 0.f;
    off[j] = ok ? yy * Wd + xx : 0;
  }
  const float* pc = prevUp + ((size_t)n * C + c0) * S;
  float v0 = 0.f, v1 = 0.f, v2 = 0.f, v3 = 0.f;
#pragma unroll
  for (int j = 0; j < 9; ++j) {
    v0 = fmaf(pc[off[j]], a[j], v0);
    v1 = fmaf(pc[(size_t)S + off[j]], a[j], v1);
    v2 = fmaf(pc[(size_t)2 * S + off[j]], a[j], v2);
    v3 = fmaf(pc[(size_t)3 * S + off[j]], a[j], v3);
  }
  float* op = out + ((size_t)n * C + c0) * S + p;
  op[0] = v0;
  op[(size_t)S] = v1;
  op[(size_t)2 * S] = v2;
  op[(size_t)3 * S] = v3;
}

// ---- final on pre-upsampled v6up: d_out[n,o,p] = bias[o] + sum_j att_j*v6up[tap] ----
__global__ __launch_bounds__(256) void final_tap_kernel(
    const float* __restrict__ att, const float* __restrict__ v6up,
    const float* __restrict__ biasf, const unsigned short* __restrict__ biasb,
    float* __restrict__ outf, unsigned short* __restrict__ outb,
    int total, const int* __restrict__ flag)
{
  const int isbf = flag[0];
  int idx = blockIdx.x * 256 + threadIdx.x;
  if (idx >= total) return;
  const int H = 128, Wd = 128;
  const int S = H * Wd;
  int p = idx % S;
  int t = idx / S;
  int o = t % 19, n = t / 19;
  int x = p % Wd, y = p / Wd;
  const float* ap = att + (size_t)n * 9 * S + p;
  const float* pc = v6up + ((size_t)n * 19 + o) * S;
  float v = isbf ? bf2f(biasb[o]) : biasf[o];
#pragma unroll
  for (int j = 0; j < 9; ++j) {
    int dy = (j / 3) * 2 - 2, dx = (j % 3) * 2 - 2;
    int yy = y + dy, xx = x + dx;
    if (yy >= 0 && yy < H && xx >= 0 && xx < Wd)
      v = fmaf(ap[(size_t)j * S], pc[yy * Wd + xx], v);
  }
  if (isbf) outb[idx] = f2bf(v);
  else      outf[idx] = v;
}

typedef __hip_bfloat16 bf16;

extern "C" void kernel_launch(void* const* d_in, const int* in_sizes, int n_in,
                              void* d_out, int out_size, void* d_ws, size_t ws_size,
                              hipStream_t stream) {
  (void)in_sizes; (void)n_in; (void)out_size; (void)ws_size;

  float* ws = (float*)d_ws;   // fp32 workspace, 13,584,385 floats = 51.8 MiB
  // persistent stage buffers
  float* t5   = ws + 1048576;    //   262,144
  float* q4   = ws + 1310720;    //   262,144
  float* k4s  = ws + 1572864;    //    65,536
  float* k4   = ws + 1638400;    //   262,144
  float* att4 = ws + 1900544;    //    18,432
  float* o4   = ws + 1918976;    // 1,048,576
  float* q3   = ws + 2967552;    //   524,288
  float* k3s  = ws + 3491840;    //   131,072
  float* k3   = ws + 3622912;    //   524,288
  float* att3 = ws + 4147200;    //    73,728
  float* o3   = ws + 4220928;    // 4,194,304
  float* v6s  = ws + 8415232;    //   155,648
  float* q2   = ws + 8570880;    // 2,097,152
  float* k2s  = ws + 10668032;   //   524,288
  float* k2   = ws + 11192320;   // 2,097,152
  float* att2 = ws + 13289472;   //   294,912
  int*   flag = (int*)(ws + 13584384);

  // conv5 scratch: part8 (8 K-slices); dead after finalize5.
  float* part8 = ws + 1310720;                       // 2,097,152, ends 3,407,872

  // split-C / split-kd scratch (temporally dead regions at their use time):
  float* scQ4   = ws + 4220928;   // 2,097,152 (o3 region)
  float* scK4s  = ws + 6318080;   // 1,048,576 (o3 region)
  float* scQ3   = ws + 8570880;   // 2,097,152 (q2 region)
  float* scK3s  = ws + 11192320;  // 1,048,576 (k2 region)
  float* scQ2   = ws + 0;         // 4,194,304 (p5..att3 regions, all dead)
  float* scK2s  = ws + 11192320;  // 2,097,152 (k2 region)
  float* scV6   = ws + 8570880;   //   622,592 (q2 region, dead after att2)
  float* scAtt  = ws + 0;         // stage4: 294,912; stage3: 589,824; stage2: 2,359,296

  // pre-upsampled prev buffers (each alive only between its upsample and apply):
  float* t5up = ws + 0;           // 1,048,576 (scAtt4 dead after att_fin4)
  float* o4up = ws + 8415232;     // 4,194,304 (v6s/q2 regions, written later)
  float* v6up = ws + 0;           //   622,592 (scAtt2 dead after att_fin2)

  probe_kernel<<<1, 64, 0, stream>>>((const unsigned short*)d_in[0], flag);

  // ---- conv5 + BN + ReLU: fused split-bf16 MFMA GEMM, single launch, split-K=8 ----
  conv5_gemm_fused_kernel<<<dim3(64, 8), 256, 0, stream>>>(
      (const float*)d_in[7], (const u16*)d_in[7],
      (const float*)d_in[3], (const u16*)d_in[3], part8, flag);
  finalize5_kernel<<<1024, 256, 0, stream>>>(
      part8, (const float*)d_in[8], (const u16*)d_in[8], t5, flag);

  // ---- localUp stage 4 (H=32, kd=128): c_hi=c3, c_lo=c40, prev=t5 ----
  conv1x1_part_kernel<<<dim3(16, 2, B * 8), 256, 0, stream>>>(
      (const float*)d_in[2], (const u16*)d_in[2],
      (const float*)d_in[11], (const u16*)d_in[11], scQ4, 1024, 128, 1024, 8, 0, flag);
  reduce_bn_kernel<<<1024, 256, 0, stream>>>(
      scQ4, (const float*)d_in[12], (const u16*)d_in[12], 1, q4, 128, 1024, 8, 262144, flag);
  conv1x1_part_kernel<<<dim3(4, 2, B * 16), 256, 0, stream>>>(
      (const float*)d_in[6], (const u16*)d_in[6],
      (const float*)d_in[13], (const u16*)d_in[13], scK4s, 2048, 128, 256, 16, 0, flag);
  reduce_bn_kernel<<<256, 256, 0, stream>>>(
      scK4s, (const float*)d_in[14], (const u16*)d_in[14], 1, k4s, 128, 256, 16, 65536, flag);
  upsample2x_kernel<<<1024, 256, 0, stream>>>(k4s, k4, 16, 16, B * 128 * 1024);
  att_part_kernel<<<128, 256, 0, stream>>>(q4, k4, scAtt, 128, 32, 32, 16, 16 * B * 1024);
  att_fin_kernel<<<8, 256, 0, stream>>>(scAtt, att4, 16, 1024, B * 1024);
  upsample2x_kernel<<<4096, 256, 0, stream>>>(t5, t5up, 16, 16, B * 512 * 1024);
  apply_tap4_kernel<<<1024, 256, 0, stream>>>(att4, t5up, o4, 512, 32, 32, B * 128 * 1024);

  // ---- localUp stage 3 (H=64, kd=64): c_hi=c2, c_lo=c30, prev=o4 ----
  conv1x1_part_kernel<<<dim3(64, 1, B * 4), 256, 0, stream>>>(
      (const float*)d_in[1], (const u16*)d_in[1],
      (const float*)d_in[15], (const u16*)d_in[15], scQ3, 512, 64, 4096, 4, 0, flag);
  reduce_bn_kernel<<<2048, 256, 0, stream>>>(
      scQ3, (const float*)d_in[16], (const u16*)d_in[16], 1, q3, 64, 4096, 4, 524288, flag);
  conv1x1_part_kernel<<<dim3(16, 1, B * 8), 256, 0, stream>>>(
      (const float*)d_in[5], (const u16*)d_in[5],
      (const float*)d_in[17], (const u16*)d_in[17], scK3s, 1024, 64, 1024, 8, 0, flag);
  reduce_bn_kernel<<<512, 256, 0, stream>>>(
      scK3s, (const float*)d_in[18], (const u16*)d_in[18], 1, k3s, 64, 1024, 8, 131072, flag);
  upsample2x_kernel<<<2048, 256, 0, stream>>>(k3s, k3, 32, 32, B * 64 * 4096);
  att_part_kernel<<<256, 256, 0, stream>>>(q3, k3, scAtt, 64, 64, 64, 8, 8 * B * 4096);
  att_fin_kernel<<<32, 256, 0, stream>>>(scAtt, att3, 8, 4096, B * 4096);
  upsample2x_kernel<<<16384, 256, 0, stream>>>(o4, o4up, 32, 32, B * 512 * 4096);
  apply_tap4_kernel<<<4096, 256, 0, stream>>>(att3, o4up, o3, 512, 64, 64, B * 128 * 4096);

  // ---- localUp stage 2 (H=128, kd=64): c_hi=c1, c_lo=c2, prev=o3; conv6 commuted ----
  conv1x1_part_kernel<<<dim3(256, 1, B * 2), 256, 0, stream>>>(
      (const float*)d_in[0], (const u16*)d_in[0],
      (const float*)d_in[19], (const u16*)d_in[19], scQ2, 256, 64, 16384, 2, 0, flag);
  reduce_bn_kernel<<<8192, 256, 0, stream>>>(
      scQ2, (const float*)d_in[20], (const u16*)d_in[20], 1, q2, 64, 16384, 2, 2097152, flag);
  conv1x1_part_kernel<<<dim3(64, 1, B * 4), 256, 0, stream>>>(
      (const float*)d_in[1], (const u16*)d_in[1],
      (const float*)d_in[21], (const u16*)d_in[21], scK2s, 512, 64, 4096, 4, 0, flag);
  reduce_bn_kernel<<<2048, 256, 0, stream>>>(
      scK2s, (const float*)d_in[22], (const u16*)d_in[22], 1, k2s, 64, 4096, 4, 524288, flag);
  upsample2x_kernel<<<8192, 256, 0, stream>>>(k2s, k2, 64, 64, B * 64 * 16384);
  att_part_kernel<<<1024, 256, 0, stream>>>(q2, k2, scAtt, 64, 128, 128, 8, 8 * B * 16384);
  att_fin_kernel<<<128, 256, 0, stream>>>(scAtt, att2, 8, 16384, B * 16384);
  // v6s = conv6(o3) at 64x64 (conv6 commutes with upsample AND the 9-tap gather)
  conv1x1_part_kernel<<<dim3(64, 1, B * 4), 256, 0, stream>>>(
      o3, (const u16*)nullptr,
      (const float*)d_in[9], (const u16*)d_in[9], scV6, 512, 19, 4096, 4, 1, flag);
  reduce_bn_kernel<<<608, 256, 0, stream>>>(
      scV6, (const float*)nullptr, (const u16*)nullptr, 0, v6s, 19, 4096, 4, 155648, flag);
  upsample2x_kernel<<<2432, 256, 0, stream>>>(v6s, v6up, 64, 64, B * 19 * 16384);
  final_tap_kernel<<<2432, 256, 0, stream>>>(
      att2, v6up, (const float*)d_in[10], (const u16*)d_in[10],
      (float*)d_out, (u16*)d_out, B * 19 * 16384, flag);
}

// Round 10
// 527.756 us; speedup vs baseline: 1.3246x; 1.3246x over previous
//
#include <hip/hip_runtime.h>
#include <hip/hip_bf16.h>
#include <math.h>

#define B 2

typedef __attribute__((ext_vector_type(8))) short bf16x8;
typedef __attribute__((ext_vector_type(4))) float f32x4;

// bf16 RNE on raw bits (inputs have no NaN/Inf)
__device__ __forceinline__ unsigned short f2bf(float f) {
  unsigned int u = __float_as_uint(f);
  return (unsigned short)((u + 0x7FFFu + ((u >> 16) & 1u)) >> 16);
}
__device__ __forceinline__ float bf2f(unsigned short h) {
  return __uint_as_float((unsigned int)h << 16);
}

typedef unsigned short u16;

// ---------------- dtype probe: flag=1 if buffer is bf16, 0 if f32 ----------------
__global__ void probe_kernel(const unsigned short* __restrict__ x, int* __restrict__ flag) {
  if (threadIdx.x == 0 && blockIdx.x == 0) {
    int sane = 0;
    for (int i = 0; i < 512; ++i) {
      int e = (x[i] >> 7) & 0xFF;
      if (e >= 97 && e <= 157) ++sane;
    }
    flag[0] = (sane >= 480) ? 1 : 0;
  }
}

// =============== conv5 via split-bf16 MFMA (f32 AND bf16 inputs, unified) ===========
// x -> hi = bf16(x), lo = bf16(x - hi); A.B ~= Ah.Bh + Ah.Bl + Al.Bh
// Materialized split buffers: each is re-read 8x by tile reuse (coalesced bf16x8),
// which beats fused recompute-per-tile (round-9 lesson: fused = 151 MB fetch, 3.9% mfma).

__global__ __launch_bounds__(256) void split_w_kernel(
    const float* __restrict__ wf, const unsigned short* __restrict__ wb,
    unsigned short* __restrict__ hi, unsigned short* __restrict__ lo,
    int k0, const int* __restrict__ flag)
{
  const int isbf = flag[0];
  int e = (blockIdx.x * 256 + threadIdx.x) * 4;     // 4,718,592 total elements
  int row = e / 9216, kl = e % 9216;
  size_t src = (size_t)row * 18432 + k0 + kl;
  ushort4 h, l;
  if (isbf) {
    h = *(const ushort4*)(wb + src);
    l.x = 0; l.y = 0; l.z = 0; l.w = 0;
  } else {
    float4 x = *(const float4*)(wf + src);
    float xs[4] = {x.x, x.y, x.z, x.w};
    unsigned short hs[4], ls[4];
#pragma unroll
    for (int i = 0; i < 4; ++i) {
      hs[i] = f2bf(xs[i]);
      ls[i] = f2bf(xs[i] - bf2f(hs[i]));
    }
    h.x = hs[0]; h.y = hs[1]; h.z = hs[2]; h.w = hs[3];
    l.x = ls[0]; l.y = ls[1]; l.z = ls[2]; l.w = ls[3];
  }
  *(ushort4*)(hi + e) = h;
  *(ushort4*)(lo + e) = l;
}

// im2col split: X[r=n*256+px][kl], K=k0+kl=c*9+t, 3x3 pad 1
__global__ __launch_bounds__(256) void im2col_split_kernel(
    const float* __restrict__ cf, const unsigned short* __restrict__ cb,
    unsigned short* __restrict__ xhi, unsigned short* __restrict__ xlo,
    int k0, const int* __restrict__ flag)
{
  const int isbf = flag[0];
  int idx = blockIdx.x * 256 + threadIdx.x;         // 4,718,592 total
  int kl = idx % 9216, r = idx / 9216;
  int K = k0 + kl;
  int c = K / 9, t = K - c * 9;
  int n = r >> 8, px = r & 255;
  int x = px & 15, y = px >> 4;
  int yy = y + t / 3 - 1, xx = x + t % 3 - 1;
  bool in = (yy >= 0 && yy < 16 && xx >= 0 && xx < 16);
  size_t src = (((size_t)n * 2048 + c) << 8) + yy * 16 + xx;
  unsigned short h, l;
  if (isbf) {
    h = in ? cb[src] : (unsigned short)0;
    l = 0;
  } else {
    float v = in ? cf[src] : 0.f;
    h = f2bf(v);
    l = f2bf(v - bf2f(h));
  }
  xhi[idx] = h;
  xlo[idx] = l;
}

// LDS XOR swizzle: permute 16B slots within each 128B row (involution, both sides).
__device__ __forceinline__ int swz(int b) { return b ^ (((b >> 7) & 7) << 4); }

// GEMM: part[q][oc][r] over K-slice; M=N=512, slice K=2304 (36 steps). 64x64 tiles.
// XCD-aware tile swizzle (T1): each XCD gets one mo-row of 8 tiles -> A panel 8x L2 reuse.
__global__ __launch_bounds__(256) void conv5_gemm_kernel(
    const unsigned short* __restrict__ Ah, const unsigned short* __restrict__ Al,
    const unsigned short* __restrict__ Bh, const unsigned short* __restrict__ Bl,
    float* __restrict__ part, int qbase)
{
  const int wgid = blockIdx.x;            // 0..63
  const int tile = (wgid & 7) * 8 + (wgid >> 3);   // bijective XCD swizzle (64 % 8 == 0)
  const int ks   = blockIdx.y;            // 0..3 split-K within phase
  const int mo = (tile >> 3) * 64;        // oc tile base
  const int no = (tile & 7) * 64;         // r tile base
  const int kb = ks * 2304;
  const int tid = threadIdx.x;
  const int w = tid >> 6, lane = tid & 63;
  const int wr = w >> 1, wc = w & 1;      // 2x2 wave grid, each wave 32x32 out

  __shared__ unsigned short sAh[4096], sAl[4096], sBh[4096], sBl[4096];  // 32 KB

  const int row0 = tid >> 3, slot = tid & 7;
  const size_t a0 = (size_t)(mo + row0) * 9216 + kb + slot * 8;
  const size_t a1 = a0 + (size_t)32 * 9216;
  const size_t b0 = (size_t)(no + row0) * 9216 + kb + slot * 8;
  const size_t b1 = b0 + (size_t)32 * 9216;
  const int w0 = swz(row0 * 128 + slot * 16);
  const int w1 = swz((row0 + 32) * 128 + slot * 16);

  f32x4 acc[2][2];
#pragma unroll
  for (int m = 0; m < 2; ++m)
#pragma unroll
    for (int nn = 0; nn < 2; ++nn) acc[m][nn] = (f32x4){0.f, 0.f, 0.f, 0.f};

  bf16x8 rah0 = *(const bf16x8*)(Ah + a0), rah1 = *(const bf16x8*)(Ah + a1);
  bf16x8 ral0 = *(const bf16x8*)(Al + a0), ral1 = *(const bf16x8*)(Al + a1);
  bf16x8 rbh0 = *(const bf16x8*)(Bh + b0), rbh1 = *(const bf16x8*)(Bh + b1);
  bf16x8 rbl0 = *(const bf16x8*)(Bl + b0), rbl1 = *(const bf16x8*)(Bl + b1);

  const int arow = wr * 32 + (lane & 15);
  const int brow = wc * 32 + (lane & 15);
  const int cb = (lane >> 4) * 16;

  for (int kk = 0; kk < 2304; kk += 64) {
    *(bf16x8*)((char*)sAh + w0) = rah0;  *(bf16x8*)((char*)sAh + w1) = rah1;
    *(bf16x8*)((char*)sAl + w0) = ral0;  *(bf16x8*)((char*)sAl + w1) = ral1;
    *(bf16x8*)((char*)sBh + w0) = rbh0;  *(bf16x8*)((char*)sBh + w1) = rbh1;
    *(bf16x8*)((char*)sBl + w0) = rbl0;  *(bf16x8*)((char*)sBl + w1) = rbl1;
    if (kk + 64 < 2304) {
      rah0 = *(const bf16x8*)(Ah + a0 + kk + 64);
      rah1 = *(const bf16x8*)(Ah + a1 + kk + 64);
      ral0 = *(const bf16x8*)(Al + a0 + kk + 64);
      ral1 = *(const bf16x8*)(Al + a1 + kk + 64);
      rbh0 = *(const bf16x8*)(Bh + b0 + kk + 64);
      rbh1 = *(const bf16x8*)(Bh + b1 + kk + 64);
      rbl0 = *(const bf16x8*)(Bl + b0 + kk + 64);
      rbl1 = *(const bf16x8*)(Bl + b1 + kk + 64);
    }
    __syncthreads();
#pragma unroll
    for (int k2 = 0; k2 < 2; ++k2) {
      const int colb = k2 * 64 + cb;
      bf16x8 fah[2], fal[2], fbh[2], fbl[2];
#pragma unroll
      for (int m = 0; m < 2; ++m) {
        fah[m] = *(const bf16x8*)((char*)sAh + swz((arow + m * 16) * 128 + colb));
        fal[m] = *(const bf16x8*)((char*)sAl + swz((arow + m * 16) * 128 + colb));
      }
#pragma unroll
      for (int nn = 0; nn < 2; ++nn) {
        fbh[nn] = *(const bf16x8*)((char*)sBh + swz((brow + nn * 16) * 128 + colb));
        fbl[nn] = *(const bf16x8*)((char*)sBl + swz((brow + nn * 16) * 128 + colb));
      }
#pragma unroll
      for (int m = 0; m < 2; ++m)
#pragma unroll
        for (int nn = 0; nn < 2; ++nn) {
          acc[m][nn] = __builtin_amdgcn_mfma_f32_16x16x32_bf16(fah[m], fbh[nn], acc[m][nn], 0, 0, 0);
          acc[m][nn] = __builtin_amdgcn_mfma_f32_16x16x32_bf16(fah[m], fbl[nn], acc[m][nn], 0, 0, 0);
          acc[m][nn] = __builtin_amdgcn_mfma_f32_16x16x32_bf16(fal[m], fbh[nn], acc[m][nn], 0, 0, 0);
        }
    }
    __syncthreads();
  }

  // C/D layout: col = lane&15 (-> r), row = (lane>>4)*4 + j (-> oc)
  const int quarter = qbase + ks;       // 0..7
#pragma unroll
  for (int m = 0; m < 2; ++m)
#pragma unroll
    for (int nn = 0; nn < 2; ++nn) {
      const int r = no + wc * 32 + nn * 16 + (lane & 15);
      const int n = r >> 8, px = r & 255;
#pragma unroll
      for (int j = 0; j < 4; ++j) {
        const int oc = mo + wr * 32 + m * 16 + (lane >> 4) * 4 + j;
        part[(size_t)quarter * 262144 + ((size_t)n * 512 + oc) * 256 + px] = acc[m][nn][j];
      }
    }
}

// sum 8 K-slices + BN + ReLU -> t5 (float4, 4 elems/thread)
__global__ __launch_bounds__(256) void finalize5_kernel(
    const float* __restrict__ part, const float* __restrict__ bnf,
    const unsigned short* __restrict__ bnb, float* __restrict__ t5,
    const int* __restrict__ flag)
{
  int i4 = (blockIdx.x * 256 + threadIdx.x) * 4;   // 262144 total
  int oc = (i4 >> 8) & 511;                        // same oc for all 4 (256 | i4 group)
  float4 s = {0.f, 0.f, 0.f, 0.f};
#pragma unroll
  for (int q = 0; q < 8; ++q) {
    float4 p = *(const float4*)(part + (size_t)q * 262144 + i4);
    s.x += p.x; s.y += p.y; s.z += p.z; s.w += p.w;
  }
  float g, b, m, v;
  if (flag[0]) {
    g = bf2f(bnb[oc]); b = bf2f(bnb[512 + oc]);
    m = bf2f(bnb[1024 + oc]); v = bf2f(bnb[1536 + oc]);
  } else {
    g = bnf[oc]; b = bnf[512 + oc]; m = bnf[1024 + oc]; v = bnf[1536 + oc];
  }
  float sc = g * rsqrtf(v + 1e-5f);
  float sh = b - m * sc;
  float4 r;
  r.x = fmaxf(s.x * sc + sh, 0.f);
  r.y = fmaxf(s.y * sc + sh, 0.f);
  r.z = fmaxf(s.z * sc + sh, 0.f);
  r.w = fmaxf(s.w * sc + sh, 0.f);
  *(float4*)(t5 + i4) = r;
}

// ---------------- split-C 1x1 conv partials (vectorized + reg double-buffer) --------
// blockIdx.z = n*KS + kc; part[kc*(B*O*S) + (n*O + o)*S + s]
__global__ __launch_bounds__(256) void conv1x1_part_kernel(
    const float* __restrict__ Xf, const unsigned short* __restrict__ Xb,
    const float* __restrict__ Wf, const unsigned short* __restrict__ Wb,
    float* __restrict__ part, int C, int O, int S, int KS, int xf32,
    const int* __restrict__ flag)
{
  const int isbf = flag[0];
  const int xbf = xf32 ? 0 : isbf;
  const int tid = threadIdx.x;
  const int sg = tid & 15, og = tid >> 4;
  const int s0 = blockIdx.x * 64;
  const int o0 = blockIdx.y * 64;
  const int n  = blockIdx.z / KS;
  const int kc = blockIdx.z % KS;
  const int CC = C / KS;
  const int cbase = kc * CC;

  __shared__ float xs[16][64];
  __shared__ float wsT[16][68];

  // load map: X tile = 256 x float4 (16B/lane), W tile likewise
  const int xc  = tid >> 4;          // 0..15 channel within tile
  const int xs4 = (tid & 15) * 4;    // s offset
  const int wo  = tid >> 2;          // 0..63 o within tile
  const int wc4 = (tid & 3) * 4;     // c offset within tile
  const int owo = o0 + wo;
  const bool wok = (owo < O);

  float acc[4][4];
#pragma unroll
  for (int i = 0; i < 4; ++i)
#pragma unroll
    for (int j = 0; j < 4; ++j) acc[i][j] = 0.f;

  // ---- prefetch first tile into registers ----
  float4 xr, wr_;
  {
    const int c0 = cbase;
    if (xbf) {
      ushort4 u = *(const ushort4*)(Xb + ((size_t)n * C + c0 + xc) * S + s0 + xs4);
      xr.x = bf2f(u.x); xr.y = bf2f(u.y); xr.z = bf2f(u.z); xr.w = bf2f(u.w);
    } else {
      xr = *(const float4*)(Xf + ((size_t)n * C + c0 + xc) * S + s0 + xs4);
    }
    if (wok) {
      if (isbf) {
        ushort4 u = *(const ushort4*)(Wb + (size_t)owo * C + c0 + wc4);
        wr_.x = bf2f(u.x); wr_.y = bf2f(u.y); wr_.z = bf2f(u.z); wr_.w = bf2f(u.w);
      } else {
        wr_ = *(const float4*)(Wf + (size_t)owo * C + c0 + wc4);
      }
    } else { wr_.x = 0.f; wr_.y = 0.f; wr_.z = 0.f; wr_.w = 0.f; }
  }

  for (int c0 = cbase; c0 < cbase + CC; c0 += 16) {
    // write staged regs -> LDS
    *(float4*)&xs[xc][xs4] = xr;
    wsT[wc4 + 0][wo] = wr_.x;
    wsT[wc4 + 1][wo] = wr_.y;
    wsT[wc4 + 2][wo] = wr_.z;
    wsT[wc4 + 3][wo] = wr_.w;
    __syncthreads();
    // issue next-tile loads early; they fly under the FMA block
    if (c0 + 16 < cbase + CC) {
      const int c1 = c0 + 16;
      if (xbf) {
        ushort4 u = *(const ushort4*)(Xb + ((size_t)n * C + c1 + xc) * S + s0 + xs4);
        xr.x = bf2f(u.x); xr.y = bf2f(u.y); xr.z = bf2f(u.z); xr.w = bf2f(u.w);
      } else {
        xr = *(const float4*)(Xf + ((size_t)n * C + c1 + xc) * S + s0 + xs4);
      }
      if (wok) {
        if (isbf) {
          ushort4 u = *(const ushort4*)(Wb + (size_t)owo * C + c1 + wc4);
          wr_.x = bf2f(u.x); wr_.y = bf2f(u.y); wr_.z = bf2f(u.z); wr_.w = bf2f(u.w);
        } else {
          wr_ = *(const float4*)(Wf + (size_t)owo * C + c1 + wc4);
        }
      }
    }
#pragma unroll
    for (int c = 0; c < 16; ++c) {
      const float4 xv = *(const float4*)&xs[c][sg * 4];
      const float4 wv = *(const float4*)&wsT[c][og * 4];
      acc[0][0] = fmaf(wv.x, xv.x, acc[0][0]);
      acc[0][1] = fmaf(wv.x, xv.y, acc[0][1]);
      acc[0][2] = fmaf(wv.x, xv.z, acc[0][2]);
      acc[0][3] = fmaf(wv.x, xv.w, acc[0][3]);
      acc[1][0] = fmaf(wv.y, xv.x, acc[1][0]);
      acc[1][1] = fmaf(wv.y, xv.y, acc[1][1]);
      acc[1][2] = fmaf(wv.y, xv.z, acc[1][2]);
      acc[1][3] = fmaf(wv.y, xv.w, acc[1][3]);
      acc[2][0] = fmaf(wv.z, xv.x, acc[2][0]);
      acc[2][1] = fmaf(wv.z, xv.y, acc[2][1]);
      acc[2][2] = fmaf(wv.z, xv.z, acc[2][2]);
      acc[2][3] = fmaf(wv.z, xv.w, acc[2][3]);
      acc[3][0] = fmaf(wv.w, xv.x, acc[3][0]);
      acc[3][1] = fmaf(wv.w, xv.y, acc[3][1]);
      acc[3][2] = fmaf(wv.w, xv.z, acc[3][2]);
      acc[3][3] = fmaf(wv.w, xv.w, acc[3][3]);
    }
    __syncthreads();
  }

  const size_t BOS = (size_t)B * O * S;
#pragma unroll
  for (int i = 0; i < 4; ++i) {
    int o = o0 + og * 4 + i;
    if (o < O) {
      float4 r;
      r.x = acc[i][0]; r.y = acc[i][1]; r.z = acc[i][2]; r.w = acc[i][3];
      *(float4*)(part + (size_t)kc * BOS + ((size_t)n * O + o) * S + s0 + sg * 4) = r;
    }
  }
}

// sum KS partials + optional BN -> Y (float4, 4 elems/thread).  total = B*O*S
__global__ __launch_bounds__(256) void reduce_bn_kernel(
    const float* __restrict__ part, const float* __restrict__ bnf,
    const unsigned short* __restrict__ bnb, int hasbn,
    float* __restrict__ Y, int O, int S, int KS, int total,
    const int* __restrict__ flag)
{
  int i4 = (blockIdx.x * 256 + threadIdx.x) * 4;
  if (i4 >= total) return;
  float4 s = {0.f, 0.f, 0.f, 0.f};
  for (int kc = 0; kc < KS; ++kc) {
    float4 p = *(const float4*)(part + (size_t)kc * total + i4);
    s.x += p.x; s.y += p.y; s.z += p.z; s.w += p.w;
  }
  float sc = 1.f, sh = 0.f;
  if (hasbn) {
    int o = (i4 / S) % O;     // same o across the 4 (S % 4 == 0)
    float g, b, m, v;
    if (flag[0]) {
      g = bf2f(bnb[o]); b = bf2f(bnb[O + o]);
      m = bf2f(bnb[2 * O + o]); v = bf2f(bnb[3 * O + o]);
    } else {
      g = bnf[o]; b = bnf[O + o]; m = bnf[2 * O + o]; v = bnf[3 * O + o];
    }
    sc = g * rsqrtf(v + 1e-5f);
    sh = b - m * sc;
  }
  float4 r;
  r.x = s.x * sc + sh;
  r.y = s.y * sc + sh;
  r.z = s.z * sc + sh;
  r.w = s.w * sc + sh;
  *(float4*)(Y + i4) = r;
}

// ---------------- bilinear 2x upsample, align_corners=True ----------------
__global__ __launch_bounds__(256) void upsample2x_kernel(
    const float* __restrict__ in, float* __restrict__ out,
    int h, int w, int total)
{
  int idx = blockIdx.x * 256 + threadIdx.x;
  if (idx >= total) return;
  const int Wd = 2 * w, Hd = 2 * h;
  int xo = idx % Wd;
  int t  = idx / Wd;
  int yo = t % Hd;
  int pl = t / Hd;
  const float rh = (float)(h - 1) / (float)(Hd - 1);
  const float rw = (float)(w - 1) / (float)(Wd - 1);
  float fy = yo * rh, fx = xo * rw;
  int y0 = (int)fy; if (y0 > h - 1) y0 = h - 1;
  int x0 = (int)fx; if (x0 > w - 1) x0 = w - 1;
  int y1 = min(y0 + 1, h - 1), x1 = min(x0 + 1, w - 1);
  float wy = fy - y0, wx = fx - x0;
  const float* p = in + (size_t)pl * h * w;
  float v00 = p[y0 * w + x0], v01 = p[y0 * w + x1];
  float v10 = p[y1 * w + x0], v11 = p[y1 * w + x1];
  out[idx] = (v00 * (1.f - wy) + v10 * wy) * (1.f - wx) +
             (v01 * (1.f - wy) + v11 * wy) * wx;
}

// ---- kd-split attention: partial dots.  pd[((kc*B + n)*9 + j)*S + p] ----
__global__ __launch_bounds__(256) void att_part_kernel(
    const float* __restrict__ q, const float* __restrict__ k,
    float* __restrict__ pd, int kd, int H, int Wd, int KC, int total)
{
  int idx = blockIdx.x * 256 + threadIdx.x;
  if (idx >= total) return;
  const int S = H * Wd;
  int p = idx % S;
  int t = idx / S;
  int n = t % B, kc = t / B;
  int x = p % Wd, y = p / Wd;
  int off[9]; bool ok[9];
#pragma unroll
  for (int j = 0; j < 9; ++j) {
    int dy = (j / 3) * 2 - 2, dx = (j % 3) * 2 - 2;
    int yy = y + dy, xx = x + dx;
    ok[j] = (yy >= 0 && yy < H && xx >= 0 && xx < Wd);
    off[j] = yy * Wd + xx;
  }
  float dot[9] = {0.f,0.f,0.f,0.f,0.f,0.f,0.f,0.f,0.f};
  const int cc = kd / KC;
  const int c0 = kc * cc;
  const float* qp = q + (size_t)n * kd * S + p;
  const float* kp = k + (size_t)n * kd * S;
  for (int c = c0; c < c0 + cc; ++c) {
    float qv = qp[(size_t)c * S];
    const float* kcp = kp + (size_t)c * S;
#pragma unroll
    for (int j = 0; j < 9; ++j)
      if (ok[j]) dot[j] = fmaf(qv, kcp[off[j]], dot[j]);
  }
  float* o = pd + ((size_t)(kc * B + n) * 9) * S + p;
#pragma unroll
  for (int j = 0; j < 9; ++j) o[(size_t)j * S] = dot[j];
}

// sum partial dots + softmax.  total = B*S
__global__ __launch_bounds__(256) void att_fin_kernel(
    const float* __restrict__ pd, float* __restrict__ att,
    int KC, int S, int total)
{
  int idx = blockIdx.x * 256 + threadIdx.x;
  if (idx >= total) return;
  int p = idx % S, n = idx / S;
  float dot[9] = {0.f,0.f,0.f,0.f,0.f,0.f,0.f,0.f,0.f};
  for (int kc = 0; kc < KC; ++kc) {
    const float* o = pd + ((size_t)(kc * B + n) * 9) * S + p;
#pragma unroll
    for (int j = 0; j < 9; ++j) dot[j] += o[(size_t)j * S];
  }
  float m = dot[0];
#pragma unroll
  for (int j = 1; j < 9; ++j) m = fmaxf(m, dot[j]);
  float e[9], ssum = 0.f;
#pragma unroll
  for (int j = 0; j < 9; ++j) { e[j] = __expf(dot[j] - m); ssum += e[j]; }
  float inv = 1.f / ssum;
#pragma unroll
  for (int j = 0; j < 9; ++j)
    att[((size_t)n * 9 + j) * S + p] = e[j] * inv;
}

// ---- tap-apply on PRE-UPSAMPLED prev: out[n,c,p] = sum_j att_j[p]*prevUp[n,c,p+D_j]
__global__ __launch_bounds__(256) void apply_tap4_kernel(
    const float* __restrict__ att, const float* __restrict__ prevUp,
    float* __restrict__ out, int C, int H, int Wd, int total4)
{
  int idx = blockIdx.x * 256 + threadIdx.x;
  if (idx >= total4) return;
  const int S = H * Wd;
  const int CQ = C >> 2;
  int p = idx % S;
  int t = idx / S;
  int cq = t % CQ, n = t / CQ;
  int c0 = cq << 2;
  int x = p % Wd, y = p / Wd;
  const float* ap = att + (size_t)n * 9 * S + p;
  float a[9]; int off[9];
#pragma unroll
  for (int j = 0; j < 9; ++j) {
    int dy = (j / 3) * 2 - 2, dx = (j % 3) * 2 - 2;
    int yy = y + dy, xx = x + dx;
    bool ok = (yy >= 0 && yy < H && xx >= 0 && xx < Wd);
    a[j]   = ok ? ap[(size_t)j * S] : 0.f;
    off[j] = ok ? yy * Wd + xx : 0;
  }
  const float* pc = prevUp + ((size_t)n * C + c0) * S;
  float v0 = 0.f, v1 = 0.f, v2 = 0.f, v3 = 0.f;
#pragma unroll
  for (int j = 0; j < 9; ++j) {
    v0 = fmaf(pc[off[j]], a[j], v0);
    v1 = fmaf(pc[(size_t)S + off[j]], a[j], v1);
    v2 = fmaf(pc[(size_t)2 * S + off[j]], a[j], v2);
    v3 = fmaf(pc[(size_t)3 * S + off[j]], a[j], v3);
  }
  float* op = out + ((size_t)n * C + c0) * S + p;
  op[0] = v0;
  op[(size_t)S] = v1;
  op[(size_t)2 * S] = v2;
  op[(size_t)3 * S] = v3;
}

// ---- final on pre-upsampled v6up: d_out[n,o,p] = bias[o] + sum_j att_j*v6up[tap] ----
__global__ __launch_bounds__(256) void final_tap_kernel(
    const float* __restrict__ att, const float* __restrict__ v6up,
    const float* __restrict__ biasf, const unsigned short* __restrict__ biasb,
    float* __restrict__ outf, unsigned short* __restrict__ outb,
    int total, const int* __restrict__ flag)
{
  const int isbf = flag[0];
  int idx = blockIdx.x * 256 + threadIdx.x;
  if (idx >= total) return;
  const int H = 128, Wd = 128;
  const int S = H * Wd;
  int p = idx % S;
  int t = idx / S;
  int o = t % 19, n = t / 19;
  int x = p % Wd, y = p / Wd;
  const float* ap = att + (size_t)n * 9 * S + p;
  const float* pc = v6up + ((size_t)n * 19 + o) * S;
  float v = isbf ? bf2f(biasb[o]) : biasf[o];
#pragma unroll
  for (int j = 0; j < 9; ++j) {
    int dy = (j / 3) * 2 - 2, dx = (j % 3) * 2 - 2;
    int yy = y + dy, xx = x + dx;
    if (yy >= 0 && yy < H && xx >= 0 && xx < Wd)
      v = fmaf(ap[(size_t)j * S], pc[yy * Wd + xx], v);
  }
  if (isbf) outb[idx] = f2bf(v);
  else      outf[idx] = v;
}

typedef __hip_bfloat16 bf16;

extern "C" void kernel_launch(void* const* d_in, const int* in_sizes, int n_in,
                              void* d_out, int out_size, void* d_ws, size_t ws_size,
                              hipStream_t stream) {
  (void)in_sizes; (void)n_in; (void)out_size; (void)ws_size;

  float* ws = (float*)d_ws;   // fp32 workspace, 13,584,385 floats = 51.8 MiB
  // persistent stage buffers
  float* t5   = ws + 1048576;    //   262,144
  float* q4   = ws + 1310720;    //   262,144
  float* k4s  = ws + 1572864;    //    65,536
  float* k4   = ws + 1638400;    //   262,144
  float* att4 = ws + 1900544;    //    18,432
  float* o4   = ws + 1918976;    // 1,048,576
  float* q3   = ws + 2967552;    //   524,288
  float* k3s  = ws + 3491840;    //   131,072
  float* k3   = ws + 3622912;    //   524,288
  float* att3 = ws + 4147200;    //    73,728
  float* o3   = ws + 4220928;    // 4,194,304
  float* v6s  = ws + 8415232;    //   155,648
  float* q2   = ws + 8570880;    // 2,097,152
  float* k2s  = ws + 10668032;   //   524,288
  float* k2   = ws + 11192320;   // 2,097,152
  float* att2 = ws + 13289472;   //   294,912
  int*   flag = (int*)(ws + 13584384);

  // conv5 scratch: part8 (8 K-slices) + 4 split buffers; all dead after finalize5.
  float* part8 = ws + 1310720;                       // 2,097,152, ends 3,407,872
  u16* whi = (u16*)(ws + 4147200);                   // each 4,718,592 bf16
  u16* wlo = (u16*)(ws + 6506496);
  u16* xhi = (u16*)(ws + 8865792);
  u16* xlo = (u16*)(ws + 11225088);                  // ends 13,584,384

  // split-C / split-kd scratch (temporally dead regions at their use time):
  float* scQ4   = ws + 4220928;   // 2,097,152 (o3 region)
  float* scK4s  = ws + 6318080;   // 1,048,576 (o3 region)
  float* scQ3   = ws + 8570880;   // 2,097,152 (q2 region)
  float* scK3s  = ws + 11192320;  // 1,048,576 (k2 region)
  float* scQ2   = ws + 0;         // 4,194,304 (p5..att3 regions, all dead)
  float* scK2s  = ws + 11192320;  // 2,097,152 (k2 region)
  float* scV6   = ws + 8570880;   //   622,592 (q2 region, dead after att2)
  float* scAtt  = ws + 0;         // stage4: 294,912; stage3: 589,824; stage2: 2,359,296

  // pre-upsampled prev buffers (each alive only between its upsample and apply):
  float* t5up = ws + 0;           // 1,048,576 (scAtt4 dead after att_fin4)
  float* o4up = ws + 8415232;     // 4,194,304 (v6s/q2 regions, written later)
  float* v6up = ws + 0;           //   622,592 (scAtt2 dead after att_fin2)

  probe_kernel<<<1, 64, 0, stream>>>((const unsigned short*)d_in[0], flag);

  // ---- conv5 + BN + ReLU: split-bf16 MFMA GEMM, 2 phases x 4 K-slices ----
  for (int ph = 0; ph < 2; ++ph) {
    const int k0 = ph * 9216;
    split_w_kernel<<<4608, 256, 0, stream>>>(
        (const float*)d_in[7], (const u16*)d_in[7], whi, wlo, k0, flag);
    im2col_split_kernel<<<18432, 256, 0, stream>>>(
        (const float*)d_in[3], (const u16*)d_in[3], xhi, xlo, k0, flag);
    conv5_gemm_kernel<<<dim3(64, 4), 256, 0, stream>>>(whi, wlo, xhi, xlo, part8, ph * 4);
  }
  finalize5_kernel<<<256, 256, 0, stream>>>(
      part8, (const float*)d_in[8], (const u16*)d_in[8], t5, flag);

  // ---- localUp stage 4 (H=32, kd=128): c_hi=c3, c_lo=c40, prev=t5 ----
  conv1x1_part_kernel<<<dim3(16, 2, B * 8), 256, 0, stream>>>(
      (const float*)d_in[2], (const u16*)d_in[2],
      (const float*)d_in[11], (const u16*)d_in[11], scQ4, 1024, 128, 1024, 8, 0, flag);
  reduce_bn_kernel<<<256, 256, 0, stream>>>(
      scQ4, (const float*)d_in[12], (const u16*)d_in[12], 1, q4, 128, 1024, 8, 262144, flag);
  conv1x1_part_kernel<<<dim3(4, 2, B * 16), 256, 0, stream>>>(
      (const float*)d_in[6], (const u16*)d_in[6],
      (const float*)d_in[13], (const u16*)d_in[13], scK4s, 2048, 128, 256, 16, 0, flag);
  reduce_bn_kernel<<<64, 256, 0, stream>>>(
      scK4s, (const float*)d_in[14], (const u16*)d_in[14], 1, k4s, 128, 256, 16, 65536, flag);
  upsample2x_kernel<<<1024, 256, 0, stream>>>(k4s, k4, 16, 16, B * 128 * 1024);
  att_part_kernel<<<128, 256, 0, stream>>>(q4, k4, scAtt, 128, 32, 32, 16, 16 * B * 1024);
  att_fin_kernel<<<8, 256, 0, stream>>>(scAtt, att4, 16, 1024, B * 1024);
  upsample2x_kernel<<<4096, 256, 0, stream>>>(t5, t5up, 16, 16, B * 512 * 1024);
  apply_tap4_kernel<<<1024, 256, 0, stream>>>(att4, t5up, o4, 512, 32, 32, B * 128 * 1024);

  // ---- localUp stage 3 (H=64, kd=64): c_hi=c2, c_lo=c30, prev=o4 ----
  conv1x1_part_kernel<<<dim3(64, 1, B * 4), 256, 0, stream>>>(
      (const float*)d_in[1], (const u16*)d_in[1],
      (const float*)d_in[15], (const u16*)d_in[15], scQ3, 512, 64, 4096, 4, 0, flag);
  reduce_bn_kernel<<<512, 256, 0, stream>>>(
      scQ3, (const float*)d_in[16], (const u16*)d_in[16], 1, q3, 64, 4096, 4, 524288, flag);
  conv1x1_part_kernel<<<dim3(16, 1, B * 8), 256, 0, stream>>>(
      (const float*)d_in[5], (const u16*)d_in[5],
      (const float*)d_in[17], (const u16*)d_in[17], scK3s, 1024, 64, 1024, 8, 0, flag);
  reduce_bn_kernel<<<128, 256, 0, stream>>>(
      scK3s, (const float*)d_in[18], (const u16*)d_in[18], 1, k3s, 64, 1024, 8, 131072, flag);
  upsample2x_kernel<<<2048, 256, 0, stream>>>(k3s, k3, 32, 32, B * 64 * 4096);
  att_part_kernel<<<256, 256, 0, stream>>>(q3, k3, scAtt, 64, 64, 64, 8, 8 * B * 4096);
  att_fin_kernel<<<32, 256, 0, stream>>>(scAtt, att3, 8, 4096, B * 4096);
  upsample2x_kernel<<<16384, 256, 0, stream>>>(o4, o4up, 32, 32, B * 512 * 4096);
  apply_tap4_kernel<<<4096, 256, 0, stream>>>(att3, o4up, o3, 512, 64, 64, B * 128 * 4096);

  // ---- localUp stage 2 (H=128, kd=64): c_hi=c1, c_lo=c2, prev=o3; conv6 commuted ----
  conv1x1_part_kernel<<<dim3(256, 1, B * 2), 256, 0, stream>>>(
      (const float*)d_in[0], (const u16*)d_in[0],
      (const float*)d_in[19], (const u16*)d_in[19], scQ2, 256, 64, 16384, 2, 0, flag);
  reduce_bn_kernel<<<2048, 256, 0, stream>>>(
      scQ2, (const float*)d_in[20], (const u16*)d_in[20], 1, q2, 64, 16384, 2, 2097152, flag);
  conv1x1_part_kernel<<<dim3(64, 1, B * 4), 256, 0, stream>>>(
      (const float*)d_in[1], (const u16*)d_in[1],
      (const float*)d_in[21], (const u16*)d_in[21], scK2s, 512, 64, 4096, 4, 0, flag);
  reduce_bn_kernel<<<512, 256, 0, stream>>>(
      scK2s, (const float*)d_in[22], (const u16*)d_in[22], 1, k2s, 64, 4096, 4, 524288, flag);
  upsample2x_kernel<<<8192, 256, 0, stream>>>(k2s, k2, 64, 64, B * 64 * 16384);
  att_part_kernel<<<1024, 256, 0, stream>>>(q2, k2, scAtt, 64, 128, 128, 8, 8 * B * 16384);
  att_fin_kernel<<<128, 256, 0, stream>>>(scAtt, att2, 8, 16384, B * 16384);
  // v6s = conv6(o3) at 64x64 (conv6 commutes with upsample AND the 9-tap gather)
  conv1x1_part_kernel<<<dim3(64, 1, B * 4), 256, 0, stream>>>(
      o3, (const u16*)nullptr,
      (const float*)d_in[9], (const u16*)d_in[9], scV6, 512, 19, 4096, 4, 1, flag);
  reduce_bn_kernel<<<152, 256, 0, stream>>>(
      scV6, (const float*)nullptr, (const u16*)nullptr, 0, v6s, 19, 4096, 4, 155648, flag);
  upsample2x_kernel<<<2432, 256, 0, stream>>>(v6s, v6up, 64, 64, B * 19 * 16384);
  final_tap_kernel<<<2432, 256, 0, stream>>>(
      att2, v6up, (const float*)d_in[10], (const u16*)d_in[10],
      (float*)d_out, (u16*)d_out, B * 19 * 16384, flag);
}

// Round 11
// 420.875 us; speedup vs baseline: 1.6610x; 1.2539x over previous
//
#include <hip/hip_runtime.h>
#include <hip/hip_bf16.h>
#include <math.h>

#define B 2

typedef __attribute__((ext_vector_type(8))) short bf16x8;
typedef __attribute__((ext_vector_type(4))) float f32x4;

__device__ __forceinline__ unsigned short f2bf(float f) {
  unsigned int u = __float_as_uint(f);
  return (unsigned short)((u + 0x7FFFu + ((u >> 16) & 1u)) >> 16);
}
__device__ __forceinline__ float bf2f(unsigned short h) {
  return __uint_as_float((unsigned int)h << 16);
}

typedef unsigned short u16;

// ---------------- dtype probe ----------------
__global__ void probe_kernel(const unsigned short* __restrict__ x, int* __restrict__ flag) {
  if (threadIdx.x == 0 && blockIdx.x == 0) {
    int sane = 0;
    for (int i = 0; i < 512; ++i) {
      int e = (x[i] >> 7) & 0xFF;
      if (e >= 97 && e <= 157) ++sane;
    }
    flag[0] = (sane >= 480) ? 1 : 0;
  }
}

// =============== conv5: split-bf16 MFMA (materialized split; round-9 lesson) ========

// merged split_w + im2col in one launch: [0,4608) W-split, [4608,23040) im2col
__global__ __launch_bounds__(256) void split_im2col_kernel(
    const float* __restrict__ wf, const u16* __restrict__ wb,
    const float* __restrict__ cf, const u16* __restrict__ cb,
    u16* __restrict__ whi, u16* __restrict__ wlo,
    u16* __restrict__ xhi, u16* __restrict__ xlo,
    int k0, const int* __restrict__ flag)
{
  const int isbf = flag[0];
  if (blockIdx.x < 4608) {
    int e = (blockIdx.x * 256 + threadIdx.x) * 4;
    int row = e / 9216, kl = e % 9216;
    size_t src = (size_t)row * 18432 + k0 + kl;
    ushort4 h, l;
    if (isbf) {
      h = *(const ushort4*)(wb + src);
      l.x = 0; l.y = 0; l.z = 0; l.w = 0;
    } else {
      float4 x = *(const float4*)(wf + src);
      float xs[4] = {x.x, x.y, x.z, x.w};
      unsigned short hs[4], ls[4];
#pragma unroll
      for (int i = 0; i < 4; ++i) {
        hs[i] = f2bf(xs[i]);
        ls[i] = f2bf(xs[i] - bf2f(hs[i]));
      }
      h.x = hs[0]; h.y = hs[1]; h.z = hs[2]; h.w = hs[3];
      l.x = ls[0]; l.y = ls[1]; l.z = ls[2]; l.w = ls[3];
    }
    *(ushort4*)(whi + e) = h;
    *(ushort4*)(wlo + e) = l;
  } else {
    int idx = (blockIdx.x - 4608) * 256 + threadIdx.x;
    int kl = idx % 9216, r = idx / 9216;
    int K = k0 + kl;
    int c = K / 9, t = K - c * 9;
    int n = r >> 8, px = r & 255;
    int x = px & 15, y = px >> 4;
    int yy = y + t / 3 - 1, xx = x + t % 3 - 1;
    bool in = (yy >= 0 && yy < 16 && xx >= 0 && xx < 16);
    size_t src = (((size_t)n * 2048 + c) << 8) + yy * 16 + xx;
    unsigned short h, l;
    if (isbf) {
      h = in ? cb[src] : (unsigned short)0;
      l = 0;
    } else {
      float v = in ? cf[src] : 0.f;
      h = f2bf(v);
      l = f2bf(v - bf2f(h));
    }
    xhi[idx] = h;
    xlo[idx] = l;
  }
}

__device__ __forceinline__ int swz(int b) { return b ^ (((b >> 7) & 7) << 4); }

__global__ __launch_bounds__(256) void conv5_gemm_kernel(
    const u16* __restrict__ Ah, const u16* __restrict__ Al,
    const u16* __restrict__ Bh, const u16* __restrict__ Bl,
    float* __restrict__ part, int qbase)
{
  const int tile = blockIdx.x;
  const int ks   = blockIdx.y;
  const int mo = (tile >> 3) * 64;
  const int no = (tile & 7) * 64;
  const int kb = ks * 2304;
  const int tid = threadIdx.x;
  const int w = tid >> 6, lane = tid & 63;
  const int wr = w >> 1, wc = w & 1;

  __shared__ u16 sAh[4096], sAl[4096], sBh[4096], sBl[4096];

  const int row0 = tid >> 3, slot = tid & 7;
  const size_t a0 = (size_t)(mo + row0) * 9216 + kb + slot * 8;
  const size_t a1 = a0 + (size_t)32 * 9216;
  const size_t b0 = (size_t)(no + row0) * 9216 + kb + slot * 8;
  const size_t b1 = b0 + (size_t)32 * 9216;
  const int w0 = swz(row0 * 128 + slot * 16);
  const int w1 = swz((row0 + 32) * 128 + slot * 16);

  f32x4 acc[2][2];
#pragma unroll
  for (int m = 0; m < 2; ++m)
#pragma unroll
    for (int nn = 0; nn < 2; ++nn) acc[m][nn] = (f32x4){0.f, 0.f, 0.f, 0.f};

  bf16x8 rah0 = *(const bf16x8*)(Ah + a0), rah1 = *(const bf16x8*)(Ah + a1);
  bf16x8 ral0 = *(const bf16x8*)(Al + a0), ral1 = *(const bf16x8*)(Al + a1);
  bf16x8 rbh0 = *(const bf16x8*)(Bh + b0), rbh1 = *(const bf16x8*)(Bh + b1);
  bf16x8 rbl0 = *(const bf16x8*)(Bl + b0), rbl1 = *(const bf16x8*)(Bl + b1);

  const int arow = wr * 32 + (lane & 15);
  const int brow = wc * 32 + (lane & 15);
  const int cb = (lane >> 4) * 16;

  for (int kk = 0; kk < 2304; kk += 64) {
    *(bf16x8*)((char*)sAh + w0) = rah0;  *(bf16x8*)((char*)sAh + w1) = rah1;
    *(bf16x8*)((char*)sAl + w0) = ral0;  *(bf16x8*)((char*)sAl + w1) = ral1;
    *(bf16x8*)((char*)sBh + w0) = rbh0;  *(bf16x8*)((char*)sBh + w1) = rbh1;
    *(bf16x8*)((char*)sBl + w0) = rbl0;  *(bf16x8*)((char*)sBl + w1) = rbl1;
    if (kk + 64 < 2304) {
      rah0 = *(const bf16x8*)(Ah + a0 + kk + 64);
      rah1 = *(const bf16x8*)(Ah + a1 + kk + 64);
      ral0 = *(const bf16x8*)(Al + a0 + kk + 64);
      ral1 = *(const bf16x8*)(Al + a1 + kk + 64);
      rbh0 = *(const bf16x8*)(Bh + b0 + kk + 64);
      rbh1 = *(const bf16x8*)(Bh + b1 + kk + 64);
      rbl0 = *(const bf16x8*)(Bl + b0 + kk + 64);
      rbl1 = *(const bf16x8*)(Bl + b1 + kk + 64);
    }
    __syncthreads();
#pragma unroll
    for (int k2 = 0; k2 < 2; ++k2) {
      const int colb = k2 * 64 + cb;
      bf16x8 fah[2], fal[2], fbh[2], fbl[2];
#pragma unroll
      for (int m = 0; m < 2; ++m) {
        fah[m] = *(const bf16x8*)((char*)sAh + swz((arow + m * 16) * 128 + colb));
        fal[m] = *(const bf16x8*)((char*)sAl + swz((arow + m * 16) * 128 + colb));
      }
#pragma unroll
      for (int nn = 0; nn < 2; ++nn) {
        fbh[nn] = *(const bf16x8*)((char*)sBh + swz((brow + nn * 16) * 128 + colb));
        fbl[nn] = *(const bf16x8*)((char*)sBl + swz((brow + nn * 16) * 128 + colb));
      }
#pragma unroll
      for (int m = 0; m < 2; ++m)
#pragma unroll
        for (int nn = 0; nn < 2; ++nn) {
          acc[m][nn] = __builtin_amdgcn_mfma_f32_16x16x32_bf16(fah[m], fbh[nn], acc[m][nn], 0, 0, 0);
          acc[m][nn] = __builtin_amdgcn_mfma_f32_16x16x32_bf16(fah[m], fbl[nn], acc[m][nn], 0, 0, 0);
          acc[m][nn] = __builtin_amdgcn_mfma_f32_16x16x32_bf16(fal[m], fbh[nn], acc[m][nn], 0, 0, 0);
        }
    }
    __syncthreads();
  }

  const int quarter = qbase + ks;
#pragma unroll
  for (int m = 0; m < 2; ++m)
#pragma unroll
    for (int nn = 0; nn < 2; ++nn) {
      const int r = no + wc * 32 + nn * 16 + (lane & 15);
      const int n = r >> 8, px = r & 255;
#pragma unroll
      for (int j = 0; j < 4; ++j) {
        const int oc = mo + wr * 32 + m * 16 + (lane >> 4) * 4 + j;
        part[(size_t)quarter * 262144 + ((size_t)n * 512 + oc) * 256 + px] = acc[m][nn][j];
      }
    }
}

__global__ __launch_bounds__(256) void finalize5_kernel(
    const float* __restrict__ part, const float* __restrict__ bnf,
    const u16* __restrict__ bnb, float* __restrict__ t5,
    const int* __restrict__ flag)
{
  int i4 = (blockIdx.x * 256 + threadIdx.x) * 4;
  int oc = (i4 >> 8) & 511;
  float4 s = {0.f, 0.f, 0.f, 0.f};
#pragma unroll
  for (int q = 0; q < 8; ++q) {
    float4 p = *(const float4*)(part + (size_t)q * 262144 + i4);
    s.x += p.x; s.y += p.y; s.z += p.z; s.w += p.w;
  }
  float g, b, m, v;
  if (flag[0]) {
    g = bf2f(bnb[oc]); b = bf2f(bnb[512 + oc]);
    m = bf2f(bnb[1024 + oc]); v = bf2f(bnb[1536 + oc]);
  } else {
    g = bnf[oc]; b = bnf[512 + oc]; m = bnf[1024 + oc]; v = bnf[1536 + oc];
  }
  float sc = g * rsqrtf(v + 1e-5f);
  float sh = b - m * sc;
  float4 r;
  r.x = fmaxf(s.x * sc + sh, 0.f);
  r.y = fmaxf(s.y * sc + sh, 0.f);
  r.z = fmaxf(s.z * sc + sh, 0.f);
  r.w = fmaxf(s.w * sc + sh, 0.f);
  *(float4*)(t5 + i4) = r;
}

// ---------------- 1x1 conv body (shared by mega + standalone) ----------------
__device__ __forceinline__ void conv_body(
    float (*xs)[64], float (*wsT)[68],
    const float* __restrict__ Xf, const u16* __restrict__ Xb,
    const float* __restrict__ Wf, const u16* __restrict__ Wb,
    const float* __restrict__ bnf, const u16* __restrict__ bnb,
    float* __restrict__ dst, int C, int O, int S, int KS, int xf32, int direct,
    int isbf, int local, int gx, int gy)
{
  const int xbf = xf32 ? 0 : isbf;
  const int tid = threadIdx.x;
  const int sg = tid & 15, og = tid >> 4;
  const int bx = local % gx;
  const int t2 = local / gx;
  const int by = t2 % gy;
  const int bz = t2 / gy;
  const int s0 = bx * 64;
  const int o0 = by * 64;
  const int n  = bz / KS;
  const int kc = bz % KS;
  const int CC = C / KS;
  const int cbase = kc * CC;

  const int xc  = tid >> 4;
  const int xs4 = (tid & 15) * 4;
  const int wo  = tid >> 2;
  const int wc4 = (tid & 3) * 4;
  const int owo = o0 + wo;
  const bool wok = (owo < O);

  float acc[4][4];
#pragma unroll
  for (int i = 0; i < 4; ++i)
#pragma unroll
    for (int j = 0; j < 4; ++j) acc[i][j] = 0.f;

  float4 xr, wr_;
  {
    const int c0 = cbase;
    if (xbf) {
      ushort4 u = *(const ushort4*)(Xb + ((size_t)n * C + c0 + xc) * S + s0 + xs4);
      xr.x = bf2f(u.x); xr.y = bf2f(u.y); xr.z = bf2f(u.z); xr.w = bf2f(u.w);
    } else {
      xr = *(const float4*)(Xf + ((size_t)n * C + c0 + xc) * S + s0 + xs4);
    }
    if (wok) {
      if (isbf) {
        ushort4 u = *(const ushort4*)(Wb + (size_t)owo * C + c0 + wc4);
        wr_.x = bf2f(u.x); wr_.y = bf2f(u.y); wr_.z = bf2f(u.z); wr_.w = bf2f(u.w);
      } else {
        wr_ = *(const float4*)(Wf + (size_t)owo * C + c0 + wc4);
      }
    } else { wr_.x = 0.f; wr_.y = 0.f; wr_.z = 0.f; wr_.w = 0.f; }
  }

  for (int c0 = cbase; c0 < cbase + CC; c0 += 16) {
    *(float4*)&xs[xc][xs4] = xr;
    wsT[wc4 + 0][wo] = wr_.x;
    wsT[wc4 + 1][wo] = wr_.y;
    wsT[wc4 + 2][wo] = wr_.z;
    wsT[wc4 + 3][wo] = wr_.w;
    __syncthreads();
    if (c0 + 16 < cbase + CC) {
      const int c1 = c0 + 16;
      if (xbf) {
        ushort4 u = *(const ushort4*)(Xb + ((size_t)n * C + c1 + xc) * S + s0 + xs4);
        xr.x = bf2f(u.x); xr.y = bf2f(u.y); xr.z = bf2f(u.z); xr.w = bf2f(u.w);
      } else {
        xr = *(const float4*)(Xf + ((size_t)n * C + c1 + xc) * S + s0 + xs4);
      }
      if (wok) {
        if (isbf) {
          ushort4 u = *(const ushort4*)(Wb + (size_t)owo * C + c1 + wc4);
          wr_.x = bf2f(u.x); wr_.y = bf2f(u.y); wr_.z = bf2f(u.z); wr_.w = bf2f(u.w);
        } else {
          wr_ = *(const float4*)(Wf + (size_t)owo * C + c1 + wc4);
        }
      }
    }
#pragma unroll
    for (int c = 0; c < 16; ++c) {
      const float4 xv = *(const float4*)&xs[c][sg * 4];
      const float4 wv = *(const float4*)&wsT[c][og * 4];
      acc[0][0] = fmaf(wv.x, xv.x, acc[0][0]);
      acc[0][1] = fmaf(wv.x, xv.y, acc[0][1]);
      acc[0][2] = fmaf(wv.x, xv.z, acc[0][2]);
      acc[0][3] = fmaf(wv.x, xv.w, acc[0][3]);
      acc[1][0] = fmaf(wv.y, xv.x, acc[1][0]);
      acc[1][1] = fmaf(wv.y, xv.y, acc[1][1]);
      acc[1][2] = fmaf(wv.y, xv.z, acc[1][2]);
      acc[1][3] = fmaf(wv.y, xv.w, acc[1][3]);
      acc[2][0] = fmaf(wv.z, xv.x, acc[2][0]);
      acc[2][1] = fmaf(wv.z, xv.y, acc[2][1]);
      acc[2][2] = fmaf(wv.z, xv.z, acc[2][2]);
      acc[2][3] = fmaf(wv.z, xv.w, acc[2][3]);
      acc[3][0] = fmaf(wv.w, xv.x, acc[3][0]);
      acc[3][1] = fmaf(wv.w, xv.y, acc[3][1]);
      acc[3][2] = fmaf(wv.w, xv.z, acc[3][2]);
      acc[3][3] = fmaf(wv.w, xv.w, acc[3][3]);
    }
    __syncthreads();
  }

  const size_t BOS = (size_t)B * O * S;
#pragma unroll
  for (int i = 0; i < 4; ++i) {
    int o = o0 + og * 4 + i;
    if (o < O) {
      float sc = 1.f, sh = 0.f;
      if (direct) {
        float g, b, m, v;
        if (isbf) {
          g = bf2f(bnb[o]); b = bf2f(bnb[O + o]);
          m = bf2f(bnb[2 * O + o]); v = bf2f(bnb[3 * O + o]);
        } else {
          g = bnf[o]; b = bnf[O + o]; m = bnf[2 * O + o]; v = bnf[3 * O + o];
        }
        sc = g * rsqrtf(v + 1e-5f);
        sh = b - m * sc;
      }
      float4 r;
      r.x = acc[i][0] * sc + sh;
      r.y = acc[i][1] * sc + sh;
      r.z = acc[i][2] * sc + sh;
      r.w = acc[i][3] * sc + sh;
      *(float4*)(dst + (size_t)kc * BOS + ((size_t)n * O + o) * S + s0 + sg * 4) = r;
    }
  }
}

// mega conv: 6 independent q/k convs in one launch
// ranges: [0,512) q4  [512,768) k4s  [768,1280) q3  [1280,1536) k3s  [1536,2048) q2(direct)  [2048,2560) k2s
struct MegaConvP {
  const void* X[6]; const void* W[6]; const void* bn[6]; float* dst[6];
};
__global__ __launch_bounds__(256) void mega_conv_kernel(MegaConvP p, const int* __restrict__ flag) {
  __shared__ float xs[16][64];
  __shared__ float wsT[16][68];
  const int isbf = flag[0];
  const int b = blockIdx.x;
  if (b < 512)
    conv_body(xs, wsT, (const float*)p.X[0], (const u16*)p.X[0], (const float*)p.W[0], (const u16*)p.W[0],
              (const float*)p.bn[0], (const u16*)p.bn[0], p.dst[0], 1024, 128, 1024, 8, 0, 0, isbf, b, 16, 2);
  else if (b < 768)
    conv_body(xs, wsT, (const float*)p.X[1], (const u16*)p.X[1], (const float*)p.W[1], (const u16*)p.W[1],
              (const float*)p.bn[1], (const u16*)p.bn[1], p.dst[1], 2048, 128, 256, 16, 0, 0, isbf, b - 512, 4, 2);
  else if (b < 1280)
    conv_body(xs, wsT, (const float*)p.X[2], (const u16*)p.X[2], (const float*)p.W[2], (const u16*)p.W[2],
              (const float*)p.bn[2], (const u16*)p.bn[2], p.dst[2], 512, 64, 4096, 4, 0, 0, isbf, b - 768, 64, 1);
  else if (b < 1536)
    conv_body(xs, wsT, (const float*)p.X[3], (const u16*)p.X[3], (const float*)p.W[3], (const u16*)p.W[3],
              (const float*)p.bn[3], (const u16*)p.bn[3], p.dst[3], 1024, 64, 1024, 8, 0, 0, isbf, b - 1280, 16, 1);
  else if (b < 2048)
    conv_body(xs, wsT, (const float*)p.X[4], (const u16*)p.X[4], (const float*)p.W[4], (const u16*)p.W[4],
              (const float*)p.bn[4], (const u16*)p.bn[4], p.dst[4], 256, 64, 16384, 1, 0, 1, isbf, b - 1536, 256, 1);
  else
    conv_body(xs, wsT, (const float*)p.X[5], (const u16*)p.X[5], (const float*)p.W[5], (const u16*)p.W[5],
              (const float*)p.bn[5], (const u16*)p.bn[5], p.dst[5], 512, 64, 4096, 4, 0, 0, isbf, b - 2048, 64, 1);
}

// ---------------- reduce body + mega reduce ----------------
__device__ __forceinline__ void reduce_body(
    const float* __restrict__ src, const float* __restrict__ bnf,
    const u16* __restrict__ bnb, float* __restrict__ dst,
    int O, int S, int KS, int total, int isbf, int local)
{
  int i4 = (local * 256 + threadIdx.x) * 4;
  if (i4 >= total) return;
  float4 s = {0.f, 0.f, 0.f, 0.f};
  for (int kc = 0; kc < KS; ++kc) {
    float4 p = *(const float4*)(src + (size_t)kc * total + i4);
    s.x += p.x; s.y += p.y; s.z += p.z; s.w += p.w;
  }
  int o = (i4 / S) % O;
  float g, b, m, v;
  if (isbf) {
    g = bf2f(bnb[o]); b = bf2f(bnb[O + o]);
    m = bf2f(bnb[2 * O + o]); v = bf2f(bnb[3 * O + o]);
  } else {
    g = bnf[o]; b = bnf[O + o]; m = bnf[2 * O + o]; v = bnf[3 * O + o];
  }
  float sc = g * rsqrtf(v + 1e-5f);
  float sh = b - m * sc;
  float4 r;
  r.x = s.x * sc + sh; r.y = s.y * sc + sh;
  r.z = s.z * sc + sh; r.w = s.w * sc + sh;
  *(float4*)(dst + i4) = r;
}

// ranges: [0,256) q4  [256,320) k4s  [320,832) q3  [832,960) k3s  [960,1472) k2s
struct MegaRedP { const float* src[5]; const void* bn[5]; float* dst[5]; };
__global__ __launch_bounds__(256) void mega_reduce_kernel(MegaRedP p, const int* __restrict__ flag) {
  const int isbf = flag[0];
  const int b = blockIdx.x;
  if (b < 256)      reduce_body(p.src[0], (const float*)p.bn[0], (const u16*)p.bn[0], p.dst[0], 128, 1024, 8, 262144, isbf, b);
  else if (b < 320) reduce_body(p.src[1], (const float*)p.bn[1], (const u16*)p.bn[1], p.dst[1], 128, 256, 16, 65536, isbf, b - 256);
  else if (b < 832) reduce_body(p.src[2], (const float*)p.bn[2], (const u16*)p.bn[2], p.dst[2], 64, 4096, 4, 524288, isbf, b - 320);
  else if (b < 960) reduce_body(p.src[3], (const float*)p.bn[3], (const u16*)p.bn[3], p.dst[3], 64, 1024, 8, 131072, isbf, b - 832);
  else              reduce_body(p.src[4], (const float*)p.bn[4], (const u16*)p.bn[4], p.dst[4], 64, 4096, 4, 524288, isbf, b - 960);
}

// standalone reduce for v6 (no BN)
__global__ __launch_bounds__(256) void reduce_plain_kernel(
    const float* __restrict__ part, float* __restrict__ Y,
    int KS, int total)
{
  int i4 = (blockIdx.x * 256 + threadIdx.x) * 4;
  if (i4 >= total) return;
  float4 s = {0.f, 0.f, 0.f, 0.f};
  for (int kc = 0; kc < KS; ++kc) {
    float4 p = *(const float4*)(part + (size_t)kc * total + i4);
    s.x += p.x; s.y += p.y; s.z += p.z; s.w += p.w;
  }
  *(float4*)(Y + i4) = s;
}

// ---------------- upsample body + mega ups ----------------
__device__ __forceinline__ void ups_body(
    const float* __restrict__ in, float* __restrict__ out,
    int h, int w, int total, int local)
{
  int idx = local * 256 + threadIdx.x;
  if (idx >= total) return;
  const int Wd = 2 * w, Hd = 2 * h;
  int xo = idx % Wd;
  int t  = idx / Wd;
  int yo = t % Hd;
  int pl = t / Hd;
  const float rh = (float)(h - 1) / (float)(Hd - 1);
  const float rw = (float)(w - 1) / (float)(Wd - 1);
  float fy = yo * rh, fx = xo * rw;
  int y0 = (int)fy; if (y0 > h - 1) y0 = h - 1;
  int x0 = (int)fx; if (x0 > w - 1) x0 = w - 1;
  int y1 = min(y0 + 1, h - 1), x1 = min(x0 + 1, w - 1);
  float wy = fy - y0, wx = fx - x0;
  const float* p = in + (size_t)pl * h * w;
  float v00 = p[y0 * w + x0], v01 = p[y0 * w + x1];
  float v10 = p[y1 * w + x0], v11 = p[y1 * w + x1];
  out[idx] = (v00 * (1.f - wy) + v10 * wy) * (1.f - wx) +
             (v01 * (1.f - wy) + v11 * wy) * wx;
}

// ranges: [0,1024) k4  [1024,3072) k3  [3072,11264) k2  [11264,15360) t5up
struct MegaUpsP { const float* in[4]; float* out[4]; };
__global__ __launch_bounds__(256) void mega_ups_kernel(MegaUpsP p) {
  const int b = blockIdx.x;
  if (b < 1024)       ups_body(p.in[0], p.out[0], 16, 16, B * 128 * 1024, b);
  else if (b < 3072)  ups_body(p.in[1], p.out[1], 32, 32, B * 64 * 4096, b - 1024);
  else if (b < 11264) ups_body(p.in[2], p.out[2], 64, 64, B * 64 * 16384, b - 3072);
  else                ups_body(p.in[3], p.out[3], 16, 16, B * 512 * 1024, b - 11264);
}

__global__ __launch_bounds__(256) void upsample2x_kernel(
    const float* __restrict__ in, float* __restrict__ out,
    int h, int w, int total)
{
  ups_body(in, out, h, w, total, blockIdx.x);
}

// ---------------- attention: part + fin bodies, mega variants ----------------
__device__ __forceinline__ void att_part_body(
    const float* __restrict__ q, const float* __restrict__ k,
    float* __restrict__ pd, int kd, int H, int Wd, int KC, int total, int local)
{
  int idx = local * 256 + threadIdx.x;
  if (idx >= total) return;
  const int S = H * Wd;
  int p = idx % S;
  int t = idx / S;
  int n = t % B, kc = t / B;
  int x = p % Wd, y = p / Wd;
  int off[9]; bool ok[9];
#pragma unroll
  for (int j = 0; j < 9; ++j) {
    int dy = (j / 3) * 2 - 2, dx = (j % 3) * 2 - 2;
    int yy = y + dy, xx = x + dx;
    ok[j] = (yy >= 0 && yy < H && xx >= 0 && xx < Wd);
    off[j] = yy * Wd + xx;
  }
  float dot[9] = {0.f,0.f,0.f,0.f,0.f,0.f,0.f,0.f,0.f};
  const int cc = kd / KC;
  const int c0 = kc * cc;
  const float* qp = q + (size_t)n * kd * S + p;
  const float* kp = k + (size_t)n * kd * S;
  for (int c = c0; c < c0 + cc; ++c) {
    float qv = qp[(size_t)c * S];
    const float* kcp = kp + (size_t)c * S;
#pragma unroll
    for (int j = 0; j < 9; ++j)
      if (ok[j]) dot[j] = fmaf(qv, kcp[off[j]], dot[j]);
  }
  float* o = pd + ((size_t)(kc * B + n) * 9) * S + p;
#pragma unroll
  for (int j = 0; j < 9; ++j) o[(size_t)j * S] = dot[j];
}

__device__ __forceinline__ void att_fin_body(
    const float* __restrict__ pd, float* __restrict__ att,
    int KC, int S, int total, int local)
{
  int idx = local * 256 + threadIdx.x;
  if (idx >= total) return;
  int p = idx % S, n = idx / S;
  float dot[9] = {0.f,0.f,0.f,0.f,0.f,0.f,0.f,0.f,0.f};
  for (int kc = 0; kc < KC; ++kc) {
    const float* o = pd + ((size_t)(kc * B + n) * 9) * S + p;
#pragma unroll
    for (int j = 0; j < 9; ++j) dot[j] += o[(size_t)j * S];
  }
  float m = dot[0];
#pragma unroll
  for (int j = 1; j < 9; ++j) m = fmaxf(m, dot[j]);
  float e[9], ssum = 0.f;
#pragma unroll
  for (int j = 0; j < 9; ++j) { e[j] = __expf(dot[j] - m); ssum += e[j]; }
  float inv = 1.f / ssum;
#pragma unroll
  for (int j = 0; j < 9; ++j)
    att[((size_t)n * 9 + j) * S + p] = e[j] * inv;
}

// ranges: [0,128) st4  [128,384) st3  [384,1408) st2
struct MegaAttPartP { const float* q[3]; const float* k[3]; float* pd[3]; };
__global__ __launch_bounds__(256) void mega_att_part_kernel(MegaAttPartP p) {
  const int b = blockIdx.x;
  if (b < 128)      att_part_body(p.q[0], p.k[0], p.pd[0], 128, 32, 32, 16, 16 * B * 1024, b);
  else if (b < 384) att_part_body(p.q[1], p.k[1], p.pd[1], 64, 64, 64, 8, 8 * B * 4096, b - 128);
  else              att_part_body(p.q[2], p.k[2], p.pd[2], 64, 128, 128, 8, 8 * B * 16384, b - 384);
}

// ranges: [0,8) st4  [8,40) st3  [40,168) st2
struct MegaAttFinP { const float* pd[3]; float* att[3]; };
__global__ __launch_bounds__(256) void mega_att_fin_kernel(MegaAttFinP p) {
  const int b = blockIdx.x;
  if (b < 8)       att_fin_body(p.pd[0], p.att[0], 16, 1024, B * 1024, b);
  else if (b < 40) att_fin_body(p.pd[1], p.att[1], 8, 4096, B * 4096, b - 8);
  else             att_fin_body(p.pd[2], p.att[2], 8, 16384, B * 16384, b - 40);
}

// ---------------- standalone v6 conv (xf32, O=19) ----------------
__global__ __launch_bounds__(256) void conv1x1_part_kernel(
    const float* __restrict__ Xf, const float* __restrict__ Wf, const u16* __restrict__ Wb,
    float* __restrict__ part, int C, int O, int S, int KS,
    const int* __restrict__ flag)
{
  __shared__ float xs[16][64];
  __shared__ float wsT[16][68];
  const int isbf = flag[0];
  const int local = blockIdx.x + blockIdx.y * gridDim.x + blockIdx.z * gridDim.x * gridDim.y;
  // grid (64,1,B*KS): local = bx + bz*64 -> decode via gx=64, gy=1
  conv_body(xs, wsT, Xf, (const u16*)nullptr, Wf, Wb,
            (const float*)nullptr, (const u16*)nullptr, part, C, O, S, KS, 1, 0,
            isbf, local, 64, 1);
}

// ---- tap-apply on PRE-UPSAMPLED prev ----
__global__ __launch_bounds__(256) void apply_tap4_kernel(
    const float* __restrict__ att, const float* __restrict__ prevUp,
    float* __restrict__ out, int C, int H, int Wd, int total4)
{
  int idx = blockIdx.x * 256 + threadIdx.x;
  if (idx >= total4) return;
  const int S = H * Wd;
  const int CQ = C >> 2;
  int p = idx % S;
  int t = idx / S;
  int cq = t % CQ, n = t / CQ;
  int c0 = cq << 2;
  int x = p % Wd, y = p / Wd;
  const float* ap = att + (size_t)n * 9 * S + p;
  float a[9]; int off[9];
#pragma unroll
  for (int j = 0; j < 9; ++j) {
    int dy = (j / 3) * 2 - 2, dx = (j % 3) * 2 - 2;
    int yy = y + dy, xx = x + dx;
    bool ok = (yy >= 0 && yy < H && xx >= 0 && xx < Wd);
    a[j]   = ok ? ap[(size_t)j * S] : 0.f;
    off[j] = ok ? yy * Wd + xx : 0;
  }
  const float* pc = prevUp + ((size_t)n * C + c0) * S;
  float v0 = 0.f, v1 = 0.f, v2 = 0.f, v3 = 0.f;
#pragma unroll
  for (int j = 0; j < 9; ++j) {
    v0 = fmaf(pc[off[j]], a[j], v0);
    v1 = fmaf(pc[(size_t)S + off[j]], a[j], v1);
    v2 = fmaf(pc[(size_t)2 * S + off[j]], a[j], v2);
    v3 = fmaf(pc[(size_t)3 * S + off[j]], a[j], v3);
  }
  float* op = out + ((size_t)n * C + c0) * S + p;
  op[0] = v0;
  op[(size_t)S] = v1;
  op[(size_t)2 * S] = v2;
  op[(size_t)3 * S] = v3;
}

// ---- final on pre-upsampled v6up ----
__global__ __launch_bounds__(256) void final_tap_kernel(
    const float* __restrict__ att, const float* __restrict__ v6up,
    const float* __restrict__ biasf, const u16* __restrict__ biasb,
    float* __restrict__ outf, u16* __restrict__ outb,
    int total, const int* __restrict__ flag)
{
  const int isbf = flag[0];
  int idx = blockIdx.x * 256 + threadIdx.x;
  if (idx >= total) return;
  const int H = 128, Wd = 128;
  const int S = H * Wd;
  int p = idx % S;
  int t = idx / S;
  int o = t % 19, n = t / 19;
  int x = p % Wd, y = p / Wd;
  const float* ap = att + (size_t)n * 9 * S + p;
  const float* pc = v6up + ((size_t)n * 19 + o) * S;
  float v = isbf ? bf2f(biasb[o]) : biasf[o];
#pragma unroll
  for (int j = 0; j < 9; ++j) {
    int dy = (j / 3) * 2 - 2, dx = (j % 3) * 2 - 2;
    int yy = y + dy, xx = x + dx;
    if (yy >= 0 && yy < H && xx >= 0 && xx < Wd)
      v = fmaf(ap[(size_t)j * S], pc[yy * Wd + xx], v);
  }
  if (isbf) outb[idx] = f2bf(v);
  else      outf[idx] = v;
}

typedef __hip_bfloat16 bf16;

extern "C" void kernel_launch(void* const* d_in, const int* in_sizes, int n_in,
                              void* d_out, int out_size, void* d_ws, size_t ws_size,
                              hipStream_t stream) {
  (void)in_sizes; (void)n_in; (void)out_size; (void)ws_size;

  float* ws = (float*)d_ws;   // fp32 workspace, 13,584,385 floats
  // persistent stage buffers (homes unchanged)
  float* t5   = ws + 1048576;    //   262,144
  float* q4   = ws + 1310720;    //   262,144
  float* k4s  = ws + 1572864;    //    65,536
  float* k4   = ws + 1638400;    //   262,144
  float* att4 = ws + 1900544;    //    18,432
  float* o4   = ws + 1918976;    // 1,048,576
  float* q3   = ws + 2967552;    //   524,288
  float* k3s  = ws + 3491840;    //   131,072
  float* k3   = ws + 3622912;    //   524,288
  float* att3 = ws + 4147200;    //    73,728
  float* o3   = ws + 4220928;    // 4,194,304
  float* v6s  = ws + 8415232;    //   155,648
  float* q2   = ws + 8570880;    // 2,097,152
  float* k2s  = ws + 10668032;   //   524,288
  float* k2   = ws + 11192320;   // 2,097,152
  float* att2 = ws + 13289472;   //   294,912
  int*   flag = (int*)(ws + 13584384);

  // conv5 scratch: dead after finalize5
  float* part8 = ws + 1310720;                       // 2,097,152
  u16* whi = (u16*)(ws + 4147200);
  u16* wlo = (u16*)(ws + 6506496);
  u16* xhi = (u16*)(ws + 8865792);
  u16* xlo = (u16*)(ws + 11225088);

  // mega-conv scratch (live step 7..8 only; verified disjoint from t5/q2/outputs):
  float* scQ4  = ws + 4220928;   // 2,097,152 -> 6,318,080
  float* scQ3  = ws + 6318080;   // 2,097,152 -> 8,415,232
  float* scK4s = ws + 0;         // 1,048,576
  float* scK3s = ws + 1918976;   // 1,048,576 -> 2,967,552
  float* scK2s = ws + 11192320;  // 2,097,152 -> 13,289,472
  // att partials (live step 10..11; scratch above dead):
  float* pd4 = ws + 1918976;     //   294,912 -> 2,213,888
  float* pd3 = ws + 2213888;     //   589,824 -> 2,803,712
  float* pd2 = ws + 4220928;     // 2,359,296 -> 6,580,224 (o3 written later)
  // pre-upsampled buffers:
  float* t5up = ws + 0;          // 1,048,576 (written step 9, used step 12)
  float* o4up = ws + 8415232;    // 4,194,304 (q2/k2 etc dead by then)
  float* scV6 = ws + 8570880;    //   622,592 (o4up dead after apply3)
  float* v6up = ws + 0;          //   622,592

  probe_kernel<<<1, 64, 0, stream>>>((const unsigned short*)d_in[0], flag);

  // ---- conv5: split-bf16 MFMA GEMM, 2 phases x 4 K-slices ----
  for (int ph = 0; ph < 2; ++ph) {
    const int k0 = ph * 9216;
    split_im2col_kernel<<<23040, 256, 0, stream>>>(
        (const float*)d_in[7], (const u16*)d_in[7],
        (const float*)d_in[3], (const u16*)d_in[3],
        whi, wlo, xhi, xlo, k0, flag);
    conv5_gemm_kernel<<<dim3(64, 4), 256, 0, stream>>>(whi, wlo, xhi, xlo, part8, ph * 4);
  }
  finalize5_kernel<<<256, 256, 0, stream>>>(
      part8, (const float*)d_in[8], (const u16*)d_in[8], t5, flag);

  // ---- mega conv: all 6 q/k 1x1 convs (inputs only; q2 direct+BN) ----
  MegaConvP pc;
  pc.X[0] = d_in[2];  pc.W[0] = d_in[11]; pc.bn[0] = d_in[12]; pc.dst[0] = scQ4;
  pc.X[1] = d_in[6];  pc.W[1] = d_in[13]; pc.bn[1] = d_in[14]; pc.dst[1] = scK4s;
  pc.X[2] = d_in[1];  pc.W[2] = d_in[15]; pc.bn[2] = d_in[16]; pc.dst[2] = scQ3;
  pc.X[3] = d_in[5];  pc.W[3] = d_in[17]; pc.bn[3] = d_in[18]; pc.dst[3] = scK3s;
  pc.X[4] = d_in[0];  pc.W[4] = d_in[19]; pc.bn[4] = d_in[20]; pc.dst[4] = q2;
  pc.X[5] = d_in[1];  pc.W[5] = d_in[21]; pc.bn[5] = d_in[22]; pc.dst[5] = scK2s;
  mega_conv_kernel<<<2560, 256, 0, stream>>>(pc, flag);

  // ---- mega reduce (5 outputs with BN) ----
  MegaRedP pr;
  pr.src[0] = scQ4;  pr.bn[0] = d_in[12]; pr.dst[0] = q4;
  pr.src[1] = scK4s; pr.bn[1] = d_in[14]; pr.dst[1] = k4s;
  pr.src[2] = scQ3;  pr.bn[2] = d_in[16]; pr.dst[2] = q3;
  pr.src[3] = scK3s; pr.bn[3] = d_in[18]; pr.dst[3] = k3s;
  pr.src[4] = scK2s; pr.bn[4] = d_in[22]; pr.dst[4] = k2s;
  mega_reduce_kernel<<<1472, 256, 0, stream>>>(pr, flag);

  // ---- mega upsample: k4, k3, k2, t5up ----
  MegaUpsP pu;
  pu.in[0] = k4s; pu.out[0] = k4;
  pu.in[1] = k3s; pu.out[1] = k3;
  pu.in[2] = k2s; pu.out[2] = k2;
  pu.in[3] = t5;  pu.out[3] = t5up;
  mega_ups_kernel<<<15360, 256, 0, stream>>>(pu);

  // ---- mega attention: partial dots then softmax (all 3 stages) ----
  MegaAttPartP pa;
  pa.q[0] = q4; pa.k[0] = k4; pa.pd[0] = pd4;
  pa.q[1] = q3; pa.k[1] = k3; pa.pd[1] = pd3;
  pa.q[2] = q2; pa.k[2] = k2; pa.pd[2] = pd2;
  mega_att_part_kernel<<<1408, 256, 0, stream>>>(pa);
  MegaAttFinP pf;
  pf.pd[0] = pd4; pf.att[0] = att4;
  pf.pd[1] = pd3; pf.att[1] = att3;
  pf.pd[2] = pd2; pf.att[2] = att2;
  mega_att_fin_kernel<<<168, 256, 0, stream>>>(pf);

  // ---- sequential tail: apply4 -> ups -> apply3 -> conv6 -> final ----
  apply_tap4_kernel<<<1024, 256, 0, stream>>>(att4, t5up, o4, 512, 32, 32, B * 128 * 1024);
  upsample2x_kernel<<<16384, 256, 0, stream>>>(o4, o4up, 32, 32, B * 512 * 4096);
  apply_tap4_kernel<<<4096, 256, 0, stream>>>(att3, o4up, o3, 512, 64, 64, B * 128 * 4096);
  conv1x1_part_kernel<<<dim3(64, 1, B * 4), 256, 0, stream>>>(
      o3, (const float*)d_in[9], (const u16*)d_in[9], scV6, 512, 19, 4096, 4, flag);
  reduce_plain_kernel<<<152, 256, 0, stream>>>(scV6, v6s, 4, 155648);
  upsample2x_kernel<<<2432, 256, 0, stream>>>(v6s, v6up, 64, 64, B * 19 * 16384);
  final_tap_kernel<<<2432, 256, 0, stream>>>(
      att2, v6up, (const float*)d_in[10], (const u16*)d_in[10],
      (float*)d_out, (u16*)d_out, B * 19 * 16384, flag);
}